// Round 4
// baseline (292.685 us; speedup 1.0000x reference)
//
#include <hip/hip_runtime.h>
#include <hip/hip_bf16.h>
#include <stdint.h>

// LocalAgg pipeline: KNN -> (factored) edge MLP -> BN+ReLU -> MLP -> BN+ReLU -> max over k.
// B=4 N=4096 C=64 O=128 K=16. Output FLOAT32 (B,N,O).
//
// 5 dispatches: knn, uv (+stat zeroing), stats1, gemm2<0> (BN2 stats), gemm2<1> (output).
// BN affines are recomputed per-block in gemm2 prologues from raw sums (no finalize kernels).
//
// Factorization: h1[b,n,k,:] = u[b,n,:] + v[b,idx[b,n,k],:]
//   u = feats @ (w1a - w1b)^T, v = feats @ w1b^T   (w1 = [w1a | w1b], each O x C)
// gemm2 (a1 @ w2^T) runs twice: PASS0 accumulates per-channel sum/sumsq (atomics),
// PASS1 recomputes and fuses BN2+ReLU+max-over-k. h2 is never materialized.
//
// KNN v3: branchless f32 packed-key scan. Inserting k >= lst[last] through the med3
// chain is a no-op, so the bubble runs unconditionally (no exec-mask churn). Self-check
// hoisted to the one wave whose chunk contains the query. Exact f64 rank-select of the
// top-15 (+self) over the merged top-24 preserves np's f64 ordering.

#define B_ 4
#define N_ 4096
#define C_ 64
#define O_ 128
#define K_ 16
#define NQ_ (B_*N_)      // 16384
#define ROWS_ (NQ_*K_)   // 262144
#define EPS_ 1e-5f
#define M1_ 12           // per-wave list (top-12 of its 256-chunk)
#define M2_ 24           // merged candidate buffer per query

typedef float f32x4 __attribute__((ext_vector_type(4)));
typedef short s16x8 __attribute__((ext_vector_type(8)));

__device__ __forceinline__ unsigned short f2bf(float f) {
  union { float f; uint32_t u; } x; x.f = f;
  uint32_t r = x.u + 0x7FFFu + ((x.u >> 16) & 1u);
  return (unsigned short)(r >> 16);
}
__device__ __forceinline__ uint32_t pack2(float a, float b) {
  return (uint32_t)f2bf(a) | ((uint32_t)f2bf(b) << 16);
}

// ---------------------------------------------------------------- KNN v3
template<bool SELF>
__device__ __forceinline__ void knn_scan(const float4* pts, int j0, int jq,
                                         float qx, float qy, float qz, float* lst) {
#pragma unroll 4
  for (int j = j0; j < j0 + N_/16; ++j) {    // wave-uniform j -> LDS broadcast
    float4 P = pts[j];
    float dx = P.x - qx, dy = P.y - qy, dz = P.z - qz;
    float d2 = fmaf(dz, dz, fmaf(dy, dy, dx * dx));
    // key: truncated f32 distance, idx in low 12 mantissa bits (positive floats
    // order as bit patterns). Self excluded only in its own wave: d2==0 -> denormal.
    uint32_t kb = (__float_as_uint(d2) & 0xFFFFF000u) | (uint32_t)j;
    float k = __uint_as_float(kb);
    if (SELF) k = (j == jq) ? 1e30f : k;
#pragma unroll
    for (int s = M1_-1; s >= 1; --s)         // branchless sorted-insert (no-op if large)
      lst[s] = __builtin_amdgcn_fmed3f(lst[s-1], lst[s], k);
    lst[0] = fminf(lst[0], k);
  }
}

// 256 blocks x 1024 threads. Block = 64 queries (one per lane); 16 waves each scan a
// 256-candidate chunk keeping top-12; log2 merge tree to 24; wave 0 exact-f64 refine.
__global__ __launch_bounds__(1024) void knn_kernel(const float* __restrict__ xyz,
                                                   int* __restrict__ idx_out) {
  __shared__ float4 pts[N_];            // 64 KiB: x,y,z,0
  __shared__ float mbuf[8 * 64 * 25];   // 50 KiB merge rows, stride 25 (bank spread)
  const int t = threadIdx.x;
  const int lane = t & 63;
  const int w = t >> 6;                 // 0..15
  const int qbase = blockIdx.x * 64;    // never straddles a batch
  const int b = qbase >> 12;
  const float* xb = xyz + (size_t)b * N_ * 3;
  for (int i = t; i < N_; i += 1024) {
    pts[i] = make_float4(xb[i*3+0], xb[i*3+1], xb[i*3+2], 0.f);
  }
  __syncthreads();
  const int q0 = qbase & (N_-1);
  const int jq = q0 + lane;             // this lane's query (local index)
  const float4 Q = pts[jq];
  float lst[M2_];
#pragma unroll
  for (int s = 0; s < M2_; ++s) lst[s] = 1e30f;   // slots [M1_,M2_) stay sentinel
  const int j0 = w * (N_/16);
  if (w == (q0 >> 8)) knn_scan<true >(pts, j0, jq, Q.x, Q.y, Q.z, lst);
  else                knn_scan<false>(pts, j0, jq, Q.x, Q.y, Q.z, lst);
  // merge tree: waves [half,2*half) publish 24 keys, waves [0,half) absorb.
  for (int half = 8; half >= 1; half >>= 1) {
    __syncthreads();
    if (w >= half && w < 2*half) {
      float* dst = mbuf + ((w - half) * 64 + lane) * 25;
#pragma unroll
      for (int s = 0; s < M2_; ++s) dst[s] = lst[s];
    }
    __syncthreads();
    if (w < half) {
      const float* src = mbuf + ((size_t)w * 64 + lane) * 25;
#pragma unroll
      for (int s = 0; s < M2_; ++s) {
        float k = src[s];
        if (!(k < lst[M2_-1])) break;   // src sorted ascending -> rest are no-ops
#pragma unroll
        for (int s2 = M2_-1; s2 >= 1; --s2)
          lst[s2] = __builtin_amdgcn_fmed3f(lst[s2-1], lst[s2], k);
        lst[0] = fminf(lst[0], k);
      }
    }
  }
  // refine: exact f64 keys for the 24 survivors; rank-count -> top-15 set (+self).
  // f64 difference-form matches np's f64 sq+sq-2dot ordering to ~1e-15 << gaps.
  if (w == 0) {
    const double qx = (double)Q.x, qy = (double)Q.y, qz = (double)Q.z;
    double dk[M2_]; int jj[M2_]; int rk[M2_];
#pragma unroll
    for (int s = 0; s < M2_; ++s) {
      int j = (int)(__float_as_uint(lst[s]) & 0xFFFu);
      jj[s] = j;
      float4 P = pts[j];
      double dx = (double)P.x - qx, dy = (double)P.y - qy, dz = (double)P.z - qz;
      double d2 = fma(dz, dz, fma(dy, dy, dx * dx));
      dk[s] = __longlong_as_double(
          (__double_as_longlong(d2) & ~0xFFFLL) | (long long)j);
      rk[s] = 0;
    }
#pragma unroll
    for (int a = 0; a < M2_; ++a)
#pragma unroll
      for (int c = a + 1; c < M2_; ++c) {
        bool lt = dk[a] < dk[c];   // keys distinct (idx packed)
        rk[c] += lt ? 1 : 0;
        rk[a] += lt ? 0 : 1;
      }
    int* op = idx_out + (size_t)(qbase + lane) * K_;
    op[0] = jq;                    // self: d2=0 exact, always reference rank 0
#pragma unroll
    for (int s = 0; s < M2_; ++s)
      if (rk[s] < K_-1) op[1 + rk[s]] = jj[s];
  }
}

// ---------------------------------------------------------------- u,v = feats @ {wA,wB}^T
// Block 0 also zeroes both stat accumulators (runs before stats1 / gemm2<0>).
__global__ __launch_bounds__(256) void uv_kernel(const float* __restrict__ feats,
                                                 const float* __restrict__ w1,
                                                 float* __restrict__ u, float* __restrict__ v,
                                                 float* __restrict__ stats1g,
                                                 float* __restrict__ stats2g) {
  __shared__ float wl[O_][129];   // +1 pad: lanes vary o -> bank spread
  __shared__ float fl[64][65];
  const int t = threadIdx.x;
  if (blockIdx.x == 0) { stats1g[t] = 0.f; stats2g[t] = 0.f; }   // t<256 covers 2x128x2
  for (int e = t; e < O_*128; e += 256) wl[e >> 7][e & 127] = w1[e];
  const int rbase = blockIdx.x * 64;
  for (int e = t; e < 64*C_; e += 256)
    fl[e >> 6][e & 63] = feats[(size_t)(rbase + (e >> 6)) * C_ + (e & 63)];
  __syncthreads();
  const int o = t & 127, rh = t >> 7;
  for (int r = rh; r < 64; r += 2) {
    float au = 0.f, av = 0.f;
#pragma unroll
    for (int c = 0; c < C_; ++c) {
      float f = fl[r][c];
      float wa = wl[o][c], wb = wl[o][C_ + c];
      au = fmaf(f, wa - wb, au);
      av = fmaf(f, wb, av);
    }
    size_t off = (size_t)(rbase + r) * O_ + o;
    u[off] = au; v[off] = av;
  }
}

// ---------------------------------------------------------------- BN1 stats over h1=u+v[idx]
// float4 per lane over channels: 32 lanes cover 128 ch; 8 row-groups of 4 rows.
__global__ __launch_bounds__(256) void stats1_kernel(const float* __restrict__ u,
                                                     const float* __restrict__ v,
                                                     const int* __restrict__ idx,
                                                     float* __restrict__ stats) {
  __shared__ float red[8][128][2];
  const int t = threadIdx.x;
  const int o4 = (t & 31) * 4, rg = t >> 5;
  const int rbase = blockIdx.x * 32;
  float s0=0.f,s1=0.f,s2=0.f,s3=0.f, q0=0.f,q1=0.f,q2=0.f,q3=0.f;
  for (int r = rg; r < 32; r += 8) {
    const int R = rbase + r;
    const int bb = R >> 12;
    float4 uu = *(const float4*)(u + (size_t)R * O_ + o4);
    const int* ip = idx + (size_t)R * K_;
#pragma unroll
    for (int k = 0; k < K_; ++k) {
      int m = ip[k];
      float4 vv = *(const float4*)(v + ((size_t)(bb << 12) + m) * O_ + o4);
      float h0 = uu.x + vv.x, h1 = uu.y + vv.y, h2 = uu.z + vv.z, h3 = uu.w + vv.w;
      s0 += h0; q0 = fmaf(h0, h0, q0);
      s1 += h1; q1 = fmaf(h1, h1, q1);
      s2 += h2; q2 = fmaf(h2, h2, q2);
      s3 += h3; q3 = fmaf(h3, h3, q3);
    }
  }
  red[rg][o4+0][0]=s0; red[rg][o4+0][1]=q0;
  red[rg][o4+1][0]=s1; red[rg][o4+1][1]=q1;
  red[rg][o4+2][0]=s2; red[rg][o4+2][1]=q2;
  red[rg][o4+3][0]=s3; red[rg][o4+3][1]=q3;
  __syncthreads();
  if (t < 128) {
    float ss = 0.f, qq = 0.f;
#pragma unroll
    for (int g = 0; g < 8; ++g) { ss += red[g][t][0]; qq += red[g][t][1]; }
    atomicAdd(&stats[t], ss);
    atomicAdd(&stats[O_ + t], qq);
  }
}

// ---------------------------------------------------------------- gemm2 (both passes)
// Block = 128 rows (8 n's x 16 k) x 128 cols, 512 threads = 8 waves in 4x2; each wave
// 32x64 via 2x4 mfma_f32_16x16x32_bf16 fragments. BN affines recomputed per block from
// raw sums. w2 converted f32->bf16 inline. a1 tile built on the fly, XOR-swizzled LDS.
#define SWZ(row, byteoff) ((byteoff) ^ (((row) & 7) << 4))

template<int PASS>
__global__ __launch_bounds__(512, 4) void gemm2_kernel(
    const float* __restrict__ u, const float* __restrict__ v, const int* __restrict__ idx,
    const float* __restrict__ stats1g, const float* __restrict__ g1, const float* __restrict__ b1,
    const float* __restrict__ w2,
    float* __restrict__ stats2g, const float* __restrict__ g2, const float* __restrict__ b2,
    float* __restrict__ out) {
  __shared__ unsigned char Al[128 * 256];   // a1 tile bf16, row stride 256B, swizzled
  __shared__ unsigned char Bl[128 * 256];   // w2   tile bf16
  __shared__ float abl[256];                // BN1 affine A|B
  __shared__ float ab2l[256];               // BN2 affine A|B (PASS1)
  __shared__ float cred[8][64][2];          // PASS0 column partials
  const int t = threadIdx.x;
  const int blk = blockIdx.x;
  const float inv = 1.0f / (float)ROWS_;
  // issue the gather index load first (deepest dependency chain)
  const int r = t >> 2, ch = (t & 3) * 32;
  const int R = blk * 128 + r;
  const int n = R >> 4, kk = R & 15, bb = n >> 12;
  const int m = idx[(size_t)n * K_ + kk];
  // recompute BN1 (and BN2) affine from raw sums
  if (t < 128) {
    float s = stats1g[t], s2 = stats1g[O_ + t];
    float mean = s * inv;
    float var = fmaf(-mean, mean, s2 * inv);
    float A = g1[t] * rsqrtf(var + EPS_);
    abl[t] = A;
    abl[O_ + t] = fmaf(-mean, A, b1[t]);
  } else if (PASS == 1 && t < 256) {
    const int o = t - 128;
    float s = stats2g[o], s2 = stats2g[O_ + o];
    float mean = s * inv;
    float var = fmaf(-mean, mean, s2 * inv);
    float A = g2[o] * rsqrtf(var + EPS_);
    ab2l[o] = A;
    ab2l[O_ + o] = fmaf(-mean, A, b2[o]);
  }
  { // stage B: w2 row o, cols c0..c0+32, f32 -> bf16
    const int o = t >> 2, c0 = (t & 3) * 32;
    const float* src = w2 + o * 128 + c0;
#pragma unroll
    for (int jj = 0; jj < 4; ++jj) {
      float4 a = *(const float4*)(src + jj * 8);
      float4 c = *(const float4*)(src + jj * 8 + 4);
      *(uint4*)(Bl + SWZ(o, o * 256 + (c0 + jj * 8) * 2)) =
          make_uint4(pack2(a.x,a.y), pack2(a.z,a.w), pack2(c.x,c.y), pack2(c.z,c.w));
    }
  }
  __syncthreads();   // abl ready for stage A
  { // stage A: a1[r][c] = relu((u+v[idx])*A1 + B1), bf16
    const float* up = u + (size_t)n * O_ + ch;
    const float* vp = v + ((size_t)(bb << 12) + m) * O_ + ch;
#pragma unroll
    for (int jj = 0; jj < 4; ++jj) {
      float4 ua = *(const float4*)(up + jj * 8);
      float4 ub = *(const float4*)(up + jj * 8 + 4);
      float4 va = *(const float4*)(vp + jj * 8);
      float4 vb = *(const float4*)(vp + jj * 8 + 4);
      const float* Ap = abl + ch + jj * 8;
      const float* Bp = abl + 128 + ch + jj * 8;
      float h0 = fmaxf(fmaf(ua.x + va.x, Ap[0], Bp[0]), 0.f);
      float h1 = fmaxf(fmaf(ua.y + va.y, Ap[1], Bp[1]), 0.f);
      float h2 = fmaxf(fmaf(ua.z + va.z, Ap[2], Bp[2]), 0.f);
      float h3 = fmaxf(fmaf(ua.w + va.w, Ap[3], Bp[3]), 0.f);
      float h4 = fmaxf(fmaf(ub.x + vb.x, Ap[4], Bp[4]), 0.f);
      float h5 = fmaxf(fmaf(ub.y + vb.y, Ap[5], Bp[5]), 0.f);
      float h6 = fmaxf(fmaf(ub.z + vb.z, Ap[6], Bp[6]), 0.f);
      float h7 = fmaxf(fmaf(ub.w + vb.w, Ap[7], Bp[7]), 0.f);
      *(uint4*)(Al + SWZ(r, r * 256 + (ch + jj * 8) * 2)) =
          make_uint4(pack2(h0,h1), pack2(h2,h3), pack2(h4,h5), pack2(h6,h7));
    }
  }
  __syncthreads();
  const int w = t >> 6, lane = t & 63;
  const int wm = w >> 1, wn = w & 1;        // 4 x 2 wave grid, wave tile 32x64
  const int r0 = lane & 15, kg = lane >> 4;
  f32x4 acc[2][4];
  f32x4 zero = {0.f, 0.f, 0.f, 0.f};
#pragma unroll
  for (int mi = 0; mi < 2; ++mi)
#pragma unroll
    for (int ni = 0; ni < 4; ++ni) acc[mi][ni] = zero;
#pragma unroll
  for (int ks = 0; ks < 4; ++ks) {
    const int cb = ks * 64 + kg * 16;       // byte offset: elem = ks*32 + kg*8
    s16x8 af[2], bf[4];
#pragma unroll
    for (int i = 0; i < 2; ++i) {
      const int ar = wm * 32 + i * 16 + r0;
      af[i] = *(const s16x8*)(Al + SWZ(ar, ar * 256 + cb));
    }
#pragma unroll
    for (int i = 0; i < 4; ++i) {
      const int br = wn * 64 + i * 16 + r0;
      bf[i] = *(const s16x8*)(Bl + SWZ(br, br * 256 + cb));
    }
#pragma unroll
    for (int mi = 0; mi < 2; ++mi)
#pragma unroll
      for (int ni = 0; ni < 4; ++ni)
        acc[mi][ni] = __builtin_amdgcn_mfma_f32_16x16x32_bf16(af[mi], bf[ni], acc[mi][ni], 0, 0, 0);
  }
  // C/D layout: col = lane&15, row = (lane>>4)*4 + i  (m89-verified)
  if (PASS == 0) {   // column sum / sumsq of h2 -> f32 atomics into stats2g
#pragma unroll
    for (int ni = 0; ni < 4; ++ni) {
      float s = 0.f, s2 = 0.f;
#pragma unroll
      for (int mi = 0; mi < 2; ++mi)
#pragma unroll
        for (int i = 0; i < 4; ++i) {
          float h = acc[mi][ni][i];
          s += h; s2 = fmaf(h, h, s2);
        }
      s += __shfl_xor(s, 16);  s += __shfl_xor(s, 32);
      s2 += __shfl_xor(s2, 16); s2 += __shfl_xor(s2, 32);
      if (lane < 16) { cred[w][ni * 16 + r0][0] = s; cred[w][ni * 16 + r0][1] = s2; }
    }
    __syncthreads();
    if (t < 128) {
      const int o = t, wn0 = o >> 6, cl = o & 63;
      float s = 0.f, s2 = 0.f;
#pragma unroll
      for (int g = 0; g < 4; ++g) {
        s += cred[g * 2 + wn0][cl][0];
        s2 += cred[g * 2 + wn0][cl][1];
      }
      atomicAdd(&stats2g[o], s);
      atomicAdd(&stats2g[O_ + o], s2);
    }
  } else {           // BN2 + ReLU + max over the 16 k-rows of each n
#pragma unroll
    for (int ni = 0; ni < 4; ++ni) {
      const int col = wn * 64 + ni * 16 + r0;
      const float A = ab2l[col], Bc = ab2l[O_ + col];
#pragma unroll
      for (int mi = 0; mi < 2; ++mi) {
        float mx = 0.f;   // == relu floor
#pragma unroll
        for (int i = 0; i < 4; ++i) mx = fmaxf(mx, fmaf(acc[mi][ni][i], A, Bc));
        mx = fmaxf(mx, __shfl_xor(mx, 16));
        mx = fmaxf(mx, __shfl_xor(mx, 32));
        if (lane < 16) {
          const int ng = blk * 8 + wm * 2 + mi;   // fragment rows = one n's 16 neighbors
          out[(size_t)ng * O_ + col] = mx;
        }
      }
    }
  }
}

extern "C" void kernel_launch(void* const* d_in, const int* in_sizes, int n_in,
                              void* d_out, int out_size, void* d_ws, size_t ws_size,
                              hipStream_t stream) {
  const float* feats = (const float*)d_in[0];
  const float* xyz   = (const float*)d_in[1];
  const float* w1    = (const float*)d_in[2];
  const float* g1    = (const float*)d_in[3];
  const float* b1    = (const float*)d_in[4];
  const float* w2    = (const float*)d_in[5];
  const float* g2    = (const float*)d_in[6];
  const float* b2    = (const float*)d_in[7];
  float* out = (float*)d_out;               // FLOAT32 output

  char* ws = (char*)d_ws;                                 // ~17 MB used
  int*   idx     = (int*)(ws + 0);                        // 1 MB
  float* u       = (float*)(ws + (1ull << 20));           // 8 MB
  float* v       = (float*)(ws + (9ull << 20));           // 8 MB
  float* stats1g = (float*)(ws + (17ull << 20));          // 256 floats
  float* stats2g = (float*)(ws + (17ull << 20) + 4096);   // 256 floats

  knn_kernel<<<256, 1024, 0, stream>>>(xyz, idx);
  uv_kernel<<<256, 256, 0, stream>>>(feats, w1, u, v, stats1g, stats2g);
  stats1_kernel<<<512, 256, 0, stream>>>(u, v, idx, stats1g);
  gemm2_kernel<0><<<2048, 512, 0, stream>>>(u, v, idx, stats1g, g1, b1, w2,
                                            stats2g, g2, b2, nullptr);
  gemm2_kernel<1><<<2048, 512, 0, stream>>>(u, v, idx, stats1g, g1, b1, w2,
                                            stats2g, g2, b2, out);
}

// Round 5
// 244.694 us; speedup vs baseline: 1.1961x; 1.1961x over previous
//
#include <hip/hip_runtime.h>
#include <hip/hip_bf16.h>
#include <stdint.h>

// LocalAgg pipeline: KNN -> (factored) edge MLP -> BN+ReLU -> MLP -> BN+ReLU -> max over k.
// B=4 N=4096 C=64 O=128 K=16. Output FLOAT32 (B,N,O).
//
// 5 dispatches: knn, uv (bf16 u,v + stat zeroing), stats1, gemm2 (single pass:
// hmax/hmin + BN2 stats), finalize (elementwise BN2+ReLU via monotone max/min trick:
// max_k relu(A*h+B) = relu(A*(A>=0?max_k h:min_k h)+B)).
//
// Factorization: h1[b,n,k,:] = u[b,n,:] + v[b,idx[b,n,k],:]
//   u = feats @ (w1a - w1b)^T, v = feats @ w1b^T   (w1 = [w1a | w1b], each O x C)
// u,v stored bf16: halves the random-row gather traffic (the R4 bottleneck:
// FETCH 33MB @ 570 GB/s effective on v-gather L2 misses).

#define B_ 4
#define N_ 4096
#define C_ 64
#define O_ 128
#define K_ 16
#define NQ_ (B_*N_)      // 16384
#define ROWS_ (NQ_*K_)   // 262144
#define EPS_ 1e-5f
#define M1_ 12           // knn per-wave list
#define M2_ 24           // knn merged candidate buffer

typedef float f32x4 __attribute__((ext_vector_type(4)));
typedef short s16x8 __attribute__((ext_vector_type(8)));

__device__ __forceinline__ unsigned short f2bf(float f) {
  union { float f; uint32_t u; } x; x.f = f;
  uint32_t r = x.u + 0x7FFFu + ((x.u >> 16) & 1u);
  return (unsigned short)(r >> 16);
}
__device__ __forceinline__ uint32_t pack2(float a, float b) {
  return (uint32_t)f2bf(a) | ((uint32_t)f2bf(b) << 16);
}
__device__ __forceinline__ float bfl(uint32_t x) { return __uint_as_float(x << 16); }
__device__ __forceinline__ float bfh(uint32_t x) { return __uint_as_float(x & 0xFFFF0000u); }

// ---------------------------------------------------------------- KNN (unchanged from R4)
template<bool SELF>
__device__ __forceinline__ void knn_scan(const float4* pts, int j0, int jq,
                                         float qx, float qy, float qz, float* lst) {
#pragma unroll 4
  for (int j = j0; j < j0 + N_/16; ++j) {    // wave-uniform j -> LDS broadcast
    float4 P = pts[j];
    float dx = P.x - qx, dy = P.y - qy, dz = P.z - qz;
    float d2 = fmaf(dz, dz, fmaf(dy, dy, dx * dx));
    uint32_t kb = (__float_as_uint(d2) & 0xFFFFF000u) | (uint32_t)j;
    float k = __uint_as_float(kb);
    if (SELF) k = (j == jq) ? 1e30f : k;
#pragma unroll
    for (int s = M1_-1; s >= 1; --s)         // branchless sorted-insert
      lst[s] = __builtin_amdgcn_fmed3f(lst[s-1], lst[s], k);
    lst[0] = fminf(lst[0], k);
  }
}

__global__ __launch_bounds__(1024) void knn_kernel(const float* __restrict__ xyz,
                                                   int* __restrict__ idx_out) {
  __shared__ float4 pts[N_];            // 64 KiB
  __shared__ float mbuf[8 * 64 * 25];   // 50 KiB merge rows, stride 25
  const int t = threadIdx.x;
  const int lane = t & 63;
  const int w = t >> 6;
  const int qbase = blockIdx.x * 64;
  const int b = qbase >> 12;
  const float* xb = xyz + (size_t)b * N_ * 3;
  for (int i = t; i < N_; i += 1024)
    pts[i] = make_float4(xb[i*3+0], xb[i*3+1], xb[i*3+2], 0.f);
  __syncthreads();
  const int q0 = qbase & (N_-1);
  const int jq = q0 + lane;
  const float4 Q = pts[jq];
  float lst[M2_];
#pragma unroll
  for (int s = 0; s < M2_; ++s) lst[s] = 1e30f;
  const int j0 = w * (N_/16);
  if (w == (q0 >> 8)) knn_scan<true >(pts, j0, jq, Q.x, Q.y, Q.z, lst);
  else                knn_scan<false>(pts, j0, jq, Q.x, Q.y, Q.z, lst);
  for (int half = 8; half >= 1; half >>= 1) {
    __syncthreads();
    if (w >= half && w < 2*half) {
      float* dst = mbuf + ((w - half) * 64 + lane) * 25;
#pragma unroll
      for (int s = 0; s < M2_; ++s) dst[s] = lst[s];
    }
    __syncthreads();
    if (w < half) {
      const float* src = mbuf + ((size_t)w * 64 + lane) * 25;
#pragma unroll
      for (int s = 0; s < M2_; ++s) {
        float k = src[s];
        if (!(k < lst[M2_-1])) break;   // src sorted ascending
#pragma unroll
        for (int s2 = M2_-1; s2 >= 1; --s2)
          lst[s2] = __builtin_amdgcn_fmed3f(lst[s2-1], lst[s2], k);
        lst[0] = fminf(lst[0], k);
      }
    }
  }
  if (w == 0) {   // exact-f64 rank-select of top-15 (+self) among 24 survivors
    const double qx = (double)Q.x, qy = (double)Q.y, qz = (double)Q.z;
    double dk[M2_]; int jj[M2_]; int rk[M2_];
#pragma unroll
    for (int s = 0; s < M2_; ++s) {
      int j = (int)(__float_as_uint(lst[s]) & 0xFFFu);
      jj[s] = j;
      float4 P = pts[j];
      double dx = (double)P.x - qx, dy = (double)P.y - qy, dz = (double)P.z - qz;
      double d2 = fma(dz, dz, fma(dy, dy, dx * dx));
      dk[s] = __longlong_as_double(
          (__double_as_longlong(d2) & ~0xFFFLL) | (long long)j);
      rk[s] = 0;
    }
#pragma unroll
    for (int a = 0; a < M2_; ++a)
#pragma unroll
      for (int c = a + 1; c < M2_; ++c) {
        bool lt = dk[a] < dk[c];
        rk[c] += lt ? 1 : 0;
        rk[a] += lt ? 0 : 1;
      }
    int* op = idx_out + (size_t)(qbase + lane) * K_;
    op[0] = jq;
#pragma unroll
    for (int s = 0; s < M2_; ++s)
      if (rk[s] < K_-1) op[1 + rk[s]] = jj[s];
  }
}

// ---------------------------------------------------------------- u,v = feats @ {wA,wB}^T (bf16 out)
__global__ __launch_bounds__(256) void uv_kernel(const float* __restrict__ feats,
                                                 const float* __restrict__ w1,
                                                 unsigned short* __restrict__ u,
                                                 unsigned short* __restrict__ v,
                                                 float* __restrict__ stats1g,
                                                 float* __restrict__ stats2g) {
  __shared__ float wl[O_][129];
  __shared__ float fl[64][65];
  const int t = threadIdx.x;
  if (blockIdx.x == 0) { stats1g[t] = 0.f; stats2g[t] = 0.f; }
  for (int e = t; e < O_*128; e += 256) wl[e >> 7][e & 127] = w1[e];
  const int rbase = blockIdx.x * 64;
  for (int e = t; e < 64*C_; e += 256)
    fl[e >> 6][e & 63] = feats[(size_t)(rbase + (e >> 6)) * C_ + (e & 63)];
  __syncthreads();
  const int o = t & 127, rh = t >> 7;
  for (int r = rh; r < 64; r += 2) {
    float au = 0.f, av = 0.f;
#pragma unroll
    for (int c = 0; c < C_; ++c) {
      float f = fl[r][c];
      float wa = wl[o][c], wb = wl[o][C_ + c];
      au = fmaf(f, wa - wb, au);
      av = fmaf(f, wb, av);
    }
    size_t off = (size_t)(rbase + r) * O_ + o;
    u[off] = f2bf(au); v[off] = f2bf(av);
  }
}

// ---------------------------------------------------------------- BN1 stats over h1=u+v[idx]
__global__ __launch_bounds__(256) void stats1_kernel(const unsigned short* __restrict__ u,
                                                     const unsigned short* __restrict__ v,
                                                     const int* __restrict__ idx,
                                                     float* __restrict__ stats) {
  __shared__ float red[8][128][2];
  const int t = threadIdx.x;
  const int o4 = (t & 31) * 4, rg = t >> 5;
  const int rbase = blockIdx.x * 32;
  float s0=0.f,s1=0.f,s2=0.f,s3=0.f, q0=0.f,q1=0.f,q2=0.f,q3=0.f;
  for (int r = rg; r < 32; r += 8) {
    const int R = rbase + r;
    const int bb = R >> 12;
    uint2 uu = *(const uint2*)(u + (size_t)R * O_ + o4);
    float u0 = bfl(uu.x), u1 = bfh(uu.x), u2 = bfl(uu.y), u3 = bfh(uu.y);
    const int* ip = idx + (size_t)R * K_;
#pragma unroll
    for (int k = 0; k < K_; ++k) {
      int m = ip[k];
      uint2 vv = *(const uint2*)(v + (((size_t)bb << 12) + m) * O_ + o4);
      float h0 = u0 + bfl(vv.x), h1 = u1 + bfh(vv.x);
      float h2 = u2 + bfl(vv.y), h3 = u3 + bfh(vv.y);
      s0 += h0; q0 = fmaf(h0, h0, q0);
      s1 += h1; q1 = fmaf(h1, h1, q1);
      s2 += h2; q2 = fmaf(h2, h2, q2);
      s3 += h3; q3 = fmaf(h3, h3, q3);
    }
  }
  red[rg][o4+0][0]=s0; red[rg][o4+0][1]=q0;
  red[rg][o4+1][0]=s1; red[rg][o4+1][1]=q1;
  red[rg][o4+2][0]=s2; red[rg][o4+2][1]=q2;
  red[rg][o4+3][0]=s3; red[rg][o4+3][1]=q3;
  __syncthreads();
  if (t < 128) {
    float ss = 0.f, qq = 0.f;
#pragma unroll
    for (int g = 0; g < 8; ++g) { ss += red[g][t][0]; qq += red[g][t][1]; }
    atomicAdd(&stats[t], ss);
    atomicAdd(&stats[O_ + t], qq);
  }
}

// ---------------------------------------------------------------- gemm2 (single pass)
// 512 blocks x 512 threads (8 waves, 4x2), all co-resident (2 blocks/CU, no tail).
// Each block: stage w2 once, then 4 row-tiles of 128 rows with reg-staged prefetch
// (idx 2 tiles ahead, v-rows + u-rows 1 tile ahead) so gather latency hides under
// MFMA+epilogue. Emits packed bf16 (hmax|hmin<<16) per (n,o) + BN2 sum/sumsq atomics.
#define SWZ(row, byteoff) ((byteoff) ^ (((row) & 7) << 4))

__global__ __launch_bounds__(512, 4) void gemm2_kernel(
    const unsigned short* __restrict__ u, const unsigned short* __restrict__ v,
    const int* __restrict__ idx,
    const float* __restrict__ stats1g, const float* __restrict__ g1, const float* __restrict__ b1,
    const float* __restrict__ w2,
    float* __restrict__ stats2g, uint32_t* __restrict__ hmm) {
  __shared__ unsigned char Al[128 * 256];   // a1 tile bf16, swizzled
  __shared__ unsigned char Bl[128 * 256];   // w2 tile bf16, swizzled
  __shared__ unsigned short ul[1024];       // 8 u-rows (bf16) of current tile
  __shared__ float abl[256];                // BN1 affine A|B
  __shared__ float cred[8][64][2];          // end-of-kernel column reduce
  const int t = threadIdx.x;
  const int blk = blockIdx.x;
  const float inv = 1.0f / (float)ROWS_;
  const int r = t >> 2, q = t & 3, ch = q * 32;
  const int rn = r >> 4, kk = r & 15;       // tile-local n, neighbor slot
  const int w = t >> 6, lane = t & 63;
  const int wm = w >> 1, wn = w & 1;        // 4x2 wave grid, wave tile 32x64
  const int r0 = lane & 15, kg = lane >> 4;

  int tile = blk * 4;
  // prologue: idx -> v prefetch (tile 0), u rows (tile 0), BN1 affine, stage B
  int m_cur = idx[(size_t)(tile * 8 + rn) * K_ + kk];
  uint4 PV[4];
  {
    const int n0 = tile * 8 + rn;
    const unsigned short* vp = v + (((size_t)(n0 >> 12) << 12) + m_cur) * O_ + ch;
#pragma unroll
    for (int jj = 0; jj < 4; ++jj) PV[jj] = *(const uint4*)(vp + jj * 8);
  }
  uint4 pu1;
  if (t < 128) {
    pu1 = *(const uint4*)(u + (size_t)tile * 1024 + t * 8);
    float s = stats1g[t], s2 = stats1g[O_ + t];
    float mean = s * inv;
    float var = fmaf(-mean, mean, s2 * inv);
    float A = g1[t] * rsqrtf(var + EPS_);
    abl[t] = A;
    abl[O_ + t] = fmaf(-mean, A, b1[t]);
  }
  { // stage B: w2 row o, 32 cols, f32 -> bf16, swizzled
    const int o = t >> 2, c0 = q * 32;
    const float* src = w2 + o * 128 + c0;
#pragma unroll
    for (int jj = 0; jj < 4; ++jj) {
      float4 a = *(const float4*)(src + jj * 8);
      float4 c = *(const float4*)(src + jj * 8 + 4);
      *(uint4*)(Bl + SWZ(o, o * 256 + (c0 + jj * 8) * 2)) =
          make_uint4(pack2(a.x,a.y), pack2(a.z,a.w), pack2(c.x,c.y), pack2(c.z,c.w));
    }
  }
  if (t < 128) *(uint4*)(ul + t * 8) = pu1;
  int m_next = idx[(size_t)((tile + 1) * 8 + rn) * K_ + kk];

  float sacc[4] = {0.f,0.f,0.f,0.f}, sacc2[4] = {0.f,0.f,0.f,0.f};
#pragma unroll
  for (int ti = 0; ti < 4; ++ti) {
    __syncthreads();   // staging (ul/Al writers) done; prev MFMA readers done
    { // stage A: a1[r][c] = relu((u+v)*A1 + B1) -> bf16, swizzled LDS
      const unsigned short* ulp = ul + rn * 128 + ch;   // wave-uniform row: broadcast
#pragma unroll
      for (int jj = 0; jj < 4; ++jj) {
        uint4 uu = *(const uint4*)(ulp + jj * 8);
        uint4 vv = PV[jj];
        const float* Ap = abl + ch + jj * 8;
        const float* Bp = abl + 128 + ch + jj * 8;
        float h0 = fmaxf(fmaf(bfl(uu.x) + bfl(vv.x), Ap[0], Bp[0]), 0.f);
        float h1 = fmaxf(fmaf(bfh(uu.x) + bfh(vv.x), Ap[1], Bp[1]), 0.f);
        float h2 = fmaxf(fmaf(bfl(uu.y) + bfl(vv.y), Ap[2], Bp[2]), 0.f);
        float h3 = fmaxf(fmaf(bfh(uu.y) + bfh(vv.y), Ap[3], Bp[3]), 0.f);
        float h4 = fmaxf(fmaf(bfl(uu.z) + bfl(vv.z), Ap[4], Bp[4]), 0.f);
        float h5 = fmaxf(fmaf(bfh(uu.z) + bfh(vv.z), Ap[5], Bp[5]), 0.f);
        float h6 = fmaxf(fmaf(bfl(uu.w) + bfl(vv.w), Ap[6], Bp[6]), 0.f);
        float h7 = fmaxf(fmaf(bfh(uu.w) + bfh(vv.w), Ap[7], Bp[7]), 0.f);
        *(uint4*)(Al + SWZ(r, r * 256 + (ch + jj * 8) * 2)) =
            make_uint4(pack2(h0,h1), pack2(h2,h3), pack2(h4,h5), pack2(h6,h7));
      }
    }
    __syncthreads();
    // prefetch next tile (loads in flight during MFMA + epilogue)
    if (ti < 3) {
      const int nn = (tile + 1) * 8 + rn;
      const unsigned short* vp = v + (((size_t)(nn >> 12) << 12) + m_next) * O_ + ch;
#pragma unroll
      for (int jj = 0; jj < 4; ++jj) PV[jj] = *(const uint4*)(vp + jj * 8);
      if (t < 128) pu1 = *(const uint4*)(u + (size_t)(tile + 1) * 1024 + t * 8);
    }
    if (ti < 2) m_next = idx[(size_t)((tile + 2) * 8 + rn) * K_ + kk];
    // MFMA: wave tile 32x64, 2x4 fragments x 4 k-steps
    f32x4 acc[2][4];
    f32x4 zero = {0.f, 0.f, 0.f, 0.f};
#pragma unroll
    for (int mi = 0; mi < 2; ++mi)
#pragma unroll
      for (int ni = 0; ni < 4; ++ni) acc[mi][ni] = zero;
#pragma unroll
    for (int ks = 0; ks < 4; ++ks) {
      const int cb = ks * 64 + kg * 16;
      s16x8 af[2], bf[4];
#pragma unroll
      for (int i = 0; i < 2; ++i) {
        const int ar = wm * 32 + i * 16 + r0;
        af[i] = *(const s16x8*)(Al + SWZ(ar, ar * 256 + cb));
      }
#pragma unroll
      for (int i = 0; i < 4; ++i) {
        const int br = wn * 64 + i * 16 + r0;
        bf[i] = *(const s16x8*)(Bl + SWZ(br, br * 256 + cb));
      }
#pragma unroll
      for (int mi = 0; mi < 2; ++mi)
#pragma unroll
        for (int ni = 0; ni < 4; ++ni)
          acc[mi][ni] = __builtin_amdgcn_mfma_f32_16x16x32_bf16(af[mi], bf[ni], acc[mi][ni], 0, 0, 0);
    }
    // write next tile's u rows (loads above have MFMA-time to land)
    if (ti < 3 && t < 128) *(uint4*)(ul + t * 8) = pu1;
    // epilogue: per-(n,o) max/min over the 16 k-rows + column sum/sumsq partials.
    // C/D layout: col = lane&15, row = kg*4 + i; fragment rows = one n's 16 neighbors.
#pragma unroll
    for (int ni = 0; ni < 4; ++ni) {
      const int col = wn * 64 + ni * 16 + r0;
#pragma unroll
      for (int mi = 0; mi < 2; ++mi) {
        float a0 = acc[mi][ni][0], a1 = acc[mi][ni][1];
        float a2 = acc[mi][ni][2], a3 = acc[mi][ni][3];
        float mx = fmaxf(fmaxf(a0, a1), fmaxf(a2, a3));
        float mn = fminf(fminf(a0, a1), fminf(a2, a3));
        mx = fmaxf(mx, __shfl_xor(mx, 16));
        mx = fmaxf(mx, __shfl_xor(mx, 32));
        mn = fminf(mn, __shfl_xor(mn, 16));
        mn = fminf(mn, __shfl_xor(mn, 32));
        if (lane < 16)
          hmm[(size_t)(tile * 8 + wm * 2 + mi) * O_ + col] = pack2(mx, mn);
        sacc[ni] += (a0 + a1) + (a2 + a3);
        sacc2[ni] += fmaf(a0, a0, fmaf(a1, a1, fmaf(a2, a2, a3 * a3)));
      }
    }
    ++tile;
  }
  // column sums -> atomics (once per block)
#pragma unroll
  for (int ni = 0; ni < 4; ++ni) {
    float s = sacc[ni], s2 = sacc2[ni];
    s += __shfl_xor(s, 16);  s += __shfl_xor(s, 32);
    s2 += __shfl_xor(s2, 16); s2 += __shfl_xor(s2, 32);
    if (lane < 16) { cred[w][ni * 16 + r0][0] = s; cred[w][ni * 16 + r0][1] = s2; }
  }
  __syncthreads();
  if (t < 128) {
    const int o = t, wn0 = o >> 6, cl = o & 63;
    float s = 0.f, s2 = 0.f;
#pragma unroll
    for (int g = 0; g < 4; ++g) {
      s += cred[g * 2 + wn0][cl][0];
      s2 += cred[g * 2 + wn0][cl][1];
    }
    atomicAdd(&stats2g[o], s);
    atomicAdd(&stats2g[O_ + o], s2);
  }
}

// ---------------------------------------------------------------- finalize: BN2+ReLU+select
__global__ __launch_bounds__(256) void finalize_kernel(const uint32_t* __restrict__ hmm,
        const float* __restrict__ stats2g, const float* __restrict__ g2,
        const float* __restrict__ b2, float* __restrict__ out) {
  __shared__ float Af[128], Bf[128];
  const int t = threadIdx.x;
  if (t < 128) {
    const float inv = 1.0f / (float)ROWS_;
    float s = stats2g[t], s2 = stats2g[O_ + t];
    float mean = s * inv;
    float var = fmaf(-mean, mean, s2 * inv);
    float A = g2[t] * rsqrtf(var + EPS_);
    Af[t] = A;
    Bf[t] = fmaf(-mean, A, b2[t]);
  }
  __syncthreads();
#pragma unroll
  for (int rep = 0; rep < 2; ++rep) {
    const int f4 = blockIdx.x * 512 + rep * 256 + t;   // uint4 index, 524288 total
    uint4 p = ((const uint4*)hmm)[f4];
    const int c = (f4 & 31) * 4;
    float4 o4;
    { float A = Af[c+0], Bb = Bf[c+0]; float sel = (A >= 0.f) ? bfl(p.x) : bfh(p.x);
      o4.x = fmaxf(fmaf(A, sel, Bb), 0.f); }
    { float A = Af[c+1], Bb = Bf[c+1]; float sel = (A >= 0.f) ? bfl(p.y) : bfh(p.y);
      o4.y = fmaxf(fmaf(A, sel, Bb), 0.f); }
    { float A = Af[c+2], Bb = Bf[c+2]; float sel = (A >= 0.f) ? bfl(p.z) : bfh(p.z);
      o4.z = fmaxf(fmaf(A, sel, Bb), 0.f); }
    { float A = Af[c+3], Bb = Bf[c+3]; float sel = (A >= 0.f) ? bfl(p.w) : bfh(p.w);
      o4.w = fmaxf(fmaf(A, sel, Bb), 0.f); }
    ((float4*)out)[f4] = o4;
  }
}

extern "C" void kernel_launch(void* const* d_in, const int* in_sizes, int n_in,
                              void* d_out, int out_size, void* d_ws, size_t ws_size,
                              hipStream_t stream) {
  const float* feats = (const float*)d_in[0];
  const float* xyz   = (const float*)d_in[1];
  const float* w1    = (const float*)d_in[2];
  const float* g1    = (const float*)d_in[3];
  const float* b1    = (const float*)d_in[4];
  const float* w2    = (const float*)d_in[5];
  const float* g2    = (const float*)d_in[6];
  const float* b2    = (const float*)d_in[7];
  float* out = (float*)d_out;

  char* ws = (char*)d_ws;                                        // ~17 MB used
  int*            idx     = (int*)(ws + 0);                      // 1 MB
  unsigned short* u       = (unsigned short*)(ws + (1ull << 20));  // 4 MB bf16
  unsigned short* v       = (unsigned short*)(ws + (5ull << 20));  // 4 MB bf16
  uint32_t*       hmm     = (uint32_t*)(ws + (9ull << 20));        // 8 MB packed (mx|mn)
  float*          stats1g = (float*)(ws + (17ull << 20));          // 1 KB
  float*          stats2g = (float*)(ws + (17ull << 20) + 4096);   // 1 KB

  knn_kernel<<<256, 1024, 0, stream>>>(xyz, idx);
  uv_kernel<<<256, 256, 0, stream>>>(feats, w1, u, v, stats1g, stats2g);
  stats1_kernel<<<512, 256, 0, stream>>>(u, v, idx, stats1g);
  gemm2_kernel<<<512, 512, 0, stream>>>(u, v, idx, stats1g, g1, b1, w2, stats2g, hmm);
  finalize_kernel<<<1024, 256, 0, stream>>>(hmm, stats2g, g2, b2, out);
}

// Round 6
// 221.219 us; speedup vs baseline: 1.3231x; 1.1061x over previous
//
#include <hip/hip_runtime.h>
#include <hip/hip_bf16.h>
#include <stdint.h>

// LocalAgg pipeline: KNN -> (factored) edge MLP -> BN+ReLU -> MLP -> BN+ReLU -> max over k.
// B=4 N=4096 C=64 O=128 K=16. Output FLOAT32 (B,N,O).
//
// 5 dispatches: knn, uv (bf16 u,v + stat zeroing), stats1, gemm2 (single pass:
// hmax/hmin + BN2 stats), finalize (BN2+ReLU via monotone trick:
// max_k relu(A*h+B) = relu(A*(A>=0?max_k h:min_k h)+B)).
//
// R6 changes: (1) gemm2 __launch_bounds__(512,2) -- R5's (512,4) made regalloc target
// 64 VGPRs and spill the PV prefetch to scratch (65MB HBM round-trip, the observed
// WRITE_SIZE=73MB); (2) XCD-contiguous block swizzle on gemm2/stats1 so each XCD's
// v-gathers cover half a batch (1MB, fits 4MB per-XCD L2); (3) stats1 uint4 gathers.

#define B_ 4
#define N_ 4096
#define C_ 64
#define O_ 128
#define K_ 16
#define NQ_ (B_*N_)      // 16384
#define ROWS_ (NQ_*K_)   // 262144
#define EPS_ 1e-5f
#define M1_ 12           // knn per-wave list
#define M2_ 24           // knn merged candidate buffer

typedef float f32x4 __attribute__((ext_vector_type(4)));
typedef short s16x8 __attribute__((ext_vector_type(8)));

__device__ __forceinline__ unsigned short f2bf(float f) {
  union { float f; uint32_t u; } x; x.f = f;
  uint32_t r = x.u + 0x7FFFu + ((x.u >> 16) & 1u);
  return (unsigned short)(r >> 16);
}
__device__ __forceinline__ uint32_t pack2(float a, float b) {
  return (uint32_t)f2bf(a) | ((uint32_t)f2bf(b) << 16);
}
__device__ __forceinline__ float bfl(uint32_t x) { return __uint_as_float(x << 16); }
__device__ __forceinline__ float bfh(uint32_t x) { return __uint_as_float(x & 0xFFFF0000u); }

// ---------------------------------------------------------------- KNN (unchanged)
template<bool SELF>
__device__ __forceinline__ void knn_scan(const float4* pts, int j0, int jq,
                                         float qx, float qy, float qz, float* lst) {
#pragma unroll 4
  for (int j = j0; j < j0 + N_/16; ++j) {    // wave-uniform j -> LDS broadcast
    float4 P = pts[j];
    float dx = P.x - qx, dy = P.y - qy, dz = P.z - qz;
    float d2 = fmaf(dz, dz, fmaf(dy, dy, dx * dx));
    uint32_t kb = (__float_as_uint(d2) & 0xFFFFF000u) | (uint32_t)j;
    float k = __uint_as_float(kb);
    if (SELF) k = (j == jq) ? 1e30f : k;
#pragma unroll
    for (int s = M1_-1; s >= 1; --s)         // branchless sorted-insert
      lst[s] = __builtin_amdgcn_fmed3f(lst[s-1], lst[s], k);
    lst[0] = fminf(lst[0], k);
  }
}

__global__ __launch_bounds__(1024) void knn_kernel(const float* __restrict__ xyz,
                                                   int* __restrict__ idx_out) {
  __shared__ float4 pts[N_];            // 64 KiB
  __shared__ float mbuf[8 * 64 * 25];   // 50 KiB merge rows, stride 25
  const int t = threadIdx.x;
  const int lane = t & 63;
  const int w = t >> 6;
  const int qbase = blockIdx.x * 64;
  const int b = qbase >> 12;
  const float* xb = xyz + (size_t)b * N_ * 3;
  for (int i = t; i < N_; i += 1024)
    pts[i] = make_float4(xb[i*3+0], xb[i*3+1], xb[i*3+2], 0.f);
  __syncthreads();
  const int q0 = qbase & (N_-1);
  const int jq = q0 + lane;
  const float4 Q = pts[jq];
  float lst[M2_];
#pragma unroll
  for (int s = 0; s < M2_; ++s) lst[s] = 1e30f;
  const int j0 = w * (N_/16);
  if (w == (q0 >> 8)) knn_scan<true >(pts, j0, jq, Q.x, Q.y, Q.z, lst);
  else                knn_scan<false>(pts, j0, jq, Q.x, Q.y, Q.z, lst);
  for (int half = 8; half >= 1; half >>= 1) {
    __syncthreads();
    if (w >= half && w < 2*half) {
      float* dst = mbuf + ((w - half) * 64 + lane) * 25;
#pragma unroll
      for (int s = 0; s < M2_; ++s) dst[s] = lst[s];
    }
    __syncthreads();
    if (w < half) {
      const float* src = mbuf + ((size_t)w * 64 + lane) * 25;
#pragma unroll
      for (int s = 0; s < M2_; ++s) {
        float k = src[s];
        if (!(k < lst[M2_-1])) break;   // src sorted ascending
#pragma unroll
        for (int s2 = M2_-1; s2 >= 1; --s2)
          lst[s2] = __builtin_amdgcn_fmed3f(lst[s2-1], lst[s2], k);
        lst[0] = fminf(lst[0], k);
      }
    }
  }
  if (w == 0) {   // exact-f64 rank-select of top-15 (+self) among 24 survivors
    const double qx = (double)Q.x, qy = (double)Q.y, qz = (double)Q.z;
    double dk[M2_]; int jj[M2_]; int rk[M2_];
#pragma unroll
    for (int s = 0; s < M2_; ++s) {
      int j = (int)(__float_as_uint(lst[s]) & 0xFFFu);
      jj[s] = j;
      float4 P = pts[j];
      double dx = (double)P.x - qx, dy = (double)P.y - qy, dz = (double)P.z - qz;
      double d2 = fma(dz, dz, fma(dy, dy, dx * dx));
      dk[s] = __longlong_as_double(
          (__double_as_longlong(d2) & ~0xFFFLL) | (long long)j);
      rk[s] = 0;
    }
#pragma unroll
    for (int a = 0; a < M2_; ++a)
#pragma unroll
      for (int c = a + 1; c < M2_; ++c) {
        bool lt = dk[a] < dk[c];
        rk[c] += lt ? 1 : 0;
        rk[a] += lt ? 0 : 1;
      }
    int* op = idx_out + (size_t)(qbase + lane) * K_;
    op[0] = jq;
#pragma unroll
    for (int s = 0; s < M2_; ++s)
      if (rk[s] < K_-1) op[1 + rk[s]] = jj[s];
  }
}

// ---------------------------------------------------------------- u,v = feats @ {wA,wB}^T (bf16 out)
__global__ __launch_bounds__(256) void uv_kernel(const float* __restrict__ feats,
                                                 const float* __restrict__ w1,
                                                 unsigned short* __restrict__ u,
                                                 unsigned short* __restrict__ v,
                                                 float* __restrict__ stats1g,
                                                 float* __restrict__ stats2g) {
  __shared__ float wl[O_][129];
  __shared__ float fl[64][65];
  const int t = threadIdx.x;
  if (blockIdx.x == 0) { stats1g[t] = 0.f; stats2g[t] = 0.f; }
  for (int e = t; e < O_*128; e += 256) wl[e >> 7][e & 127] = w1[e];
  const int rbase = blockIdx.x * 64;
  for (int e = t; e < 64*C_; e += 256)
    fl[e >> 6][e & 63] = feats[(size_t)(rbase + (e >> 6)) * C_ + (e & 63)];
  __syncthreads();
  const int o = t & 127, rh = t >> 7;
  for (int r = rh; r < 64; r += 2) {
    float au = 0.f, av = 0.f;
#pragma unroll
    for (int c = 0; c < C_; ++c) {
      float f = fl[r][c];
      float wa = wl[o][c], wb = wl[o][C_ + c];
      au = fmaf(f, wa - wb, au);
      av = fmaf(f, wb, av);
    }
    size_t off = (size_t)(rbase + r) * O_ + o;
    u[off] = f2bf(au); v[off] = f2bf(av);
  }
}

// ---------------------------------------------------------------- BN1 stats over h1=u+v[idx]
// uint4 per lane (8 ch), 16 lanes cover a 256B row. XCD-contiguous block swizzle.
__global__ __launch_bounds__(256) void stats1_kernel(const unsigned short* __restrict__ u,
                                                     const unsigned short* __restrict__ v,
                                                     const int* __restrict__ idx,
                                                     float* __restrict__ stats) {
  __shared__ float red[16][128][2];   // 16 KB
  const int t = threadIdx.x;
  const int bid = blockIdx.x;
  const int blk = (bid & 7) * 64 + (bid >> 3);   // XCD i -> rows [i*2048,(i+1)*2048)
  const int o8 = (t & 15) * 8, rg = t >> 4;      // 16 lanes x 16 row-groups
  const int rbase = blk * 32;
  float s[8], q[8];
#pragma unroll
  for (int i = 0; i < 8; ++i) { s[i] = 0.f; q[i] = 0.f; }
#pragma unroll
  for (int r = rg; r < 32; r += 16) {            // 2 rows per thread
    const int R = rbase + r;
    const int bb = R >> 12;
    uint4 uu = *(const uint4*)(u + (size_t)R * O_ + o8);
    float uf[8] = { bfl(uu.x), bfh(uu.x), bfl(uu.y), bfh(uu.y),
                    bfl(uu.z), bfh(uu.z), bfl(uu.w), bfh(uu.w) };
    int4 i0 = *(const int4*)(idx + (size_t)R * K_);
    int4 i1 = *(const int4*)(idx + (size_t)R * K_ + 4);
    int4 i2 = *(const int4*)(idx + (size_t)R * K_ + 8);
    int4 i3 = *(const int4*)(idx + (size_t)R * K_ + 12);
    int mi[16] = { i0.x,i0.y,i0.z,i0.w, i1.x,i1.y,i1.z,i1.w,
                   i2.x,i2.y,i2.z,i2.w, i3.x,i3.y,i3.z,i3.w };
    const unsigned short* vb = v + ((size_t)bb << 12) * O_ + o8;
#pragma unroll
    for (int k = 0; k < K_; ++k) {
      uint4 vv = *(const uint4*)(vb + (size_t)mi[k] * O_);
      float h;
      h = uf[0] + bfl(vv.x); s[0] += h; q[0] = fmaf(h, h, q[0]);
      h = uf[1] + bfh(vv.x); s[1] += h; q[1] = fmaf(h, h, q[1]);
      h = uf[2] + bfl(vv.y); s[2] += h; q[2] = fmaf(h, h, q[2]);
      h = uf[3] + bfh(vv.y); s[3] += h; q[3] = fmaf(h, h, q[3]);
      h = uf[4] + bfl(vv.z); s[4] += h; q[4] = fmaf(h, h, q[4]);
      h = uf[5] + bfh(vv.z); s[5] += h; q[5] = fmaf(h, h, q[5]);
      h = uf[6] + bfl(vv.w); s[6] += h; q[6] = fmaf(h, h, q[6]);
      h = uf[7] + bfh(vv.w); s[7] += h; q[7] = fmaf(h, h, q[7]);
    }
  }
#pragma unroll
  for (int i = 0; i < 8; ++i) { red[rg][o8 + i][0] = s[i]; red[rg][o8 + i][1] = q[i]; }
  __syncthreads();
  if (t < 128) {
    float ss = 0.f, qq = 0.f;
#pragma unroll
    for (int g = 0; g < 16; ++g) { ss += red[g][t][0]; qq += red[g][t][1]; }
    atomicAdd(&stats[t], ss);
    atomicAdd(&stats[O_ + t], qq);
  }
}

// ---------------------------------------------------------------- gemm2 (single pass)
// 512 blocks x 512 threads (8 waves, 4x2), 2 blocks/CU (LDS-bound). XCD-contiguous
// tile swizzle. 4 row-tiles/block with reg-staged prefetch. (512,2) bounds: VGPR cap
// 256 so the PV/pu1 prefetch registers never spill (R5 regression).
#define SWZ(row, byteoff) ((byteoff) ^ (((row) & 7) << 4))

__global__ __launch_bounds__(512, 2) void gemm2_kernel(
    const unsigned short* __restrict__ u, const unsigned short* __restrict__ v,
    const int* __restrict__ idx,
    const float* __restrict__ stats1g, const float* __restrict__ g1, const float* __restrict__ b1,
    const float* __restrict__ w2,
    float* __restrict__ stats2g, uint32_t* __restrict__ hmm) {
  __shared__ unsigned char Al[128 * 256];   // a1 tile bf16, swizzled
  __shared__ unsigned char Bl[128 * 256];   // w2 tile bf16, swizzled
  __shared__ unsigned short ul[1024];       // 8 u-rows (bf16) of current tile
  __shared__ float abl[256];                // BN1 affine A|B
  __shared__ float cred[8][64][2];          // end-of-kernel column reduce
  const int t = threadIdx.x;
  const int bid = blockIdx.x;
  const int blk = (bid & 7) * 64 + (bid >> 3);   // XCD i -> tiles of half a batch
  const float inv = 1.0f / (float)ROWS_;
  const int r = t >> 2, q = t & 3, ch = q * 32;
  const int rn = r >> 4, kk = r & 15;       // tile-local n, neighbor slot
  const int w = t >> 6, lane = t & 63;
  const int wm = w >> 1, wn = w & 1;        // 4x2 wave grid, wave tile 32x64
  const int r0 = lane & 15, kg = lane >> 4;

  int tile = blk * 4;
  // prologue: idx -> v prefetch (tile 0), u rows (tile 0), BN1 affine, stage B
  int m_cur = idx[(size_t)(tile * 8 + rn) * K_ + kk];
  uint4 PV[4];
  {
    const int n0 = tile * 8 + rn;
    const unsigned short* vp = v + (((size_t)(n0 >> 12) << 12) + m_cur) * O_ + ch;
#pragma unroll
    for (int jj = 0; jj < 4; ++jj) PV[jj] = *(const uint4*)(vp + jj * 8);
  }
  uint4 pu1;
  if (t < 128) {
    pu1 = *(const uint4*)(u + (size_t)tile * 1024 + t * 8);
    float s = stats1g[t], s2 = stats1g[O_ + t];
    float mean = s * inv;
    float var = fmaf(-mean, mean, s2 * inv);
    float A = g1[t] * rsqrtf(var + EPS_);
    abl[t] = A;
    abl[O_ + t] = fmaf(-mean, A, b1[t]);
  }
  { // stage B: w2 row o, 32 cols, f32 -> bf16, swizzled
    const int o = t >> 2, c0 = q * 32;
    const float* src = w2 + o * 128 + c0;
#pragma unroll
    for (int jj = 0; jj < 4; ++jj) {
      float4 a = *(const float4*)(src + jj * 8);
      float4 c = *(const float4*)(src + jj * 8 + 4);
      *(uint4*)(Bl + SWZ(o, o * 256 + (c0 + jj * 8) * 2)) =
          make_uint4(pack2(a.x,a.y), pack2(a.z,a.w), pack2(c.x,c.y), pack2(c.z,c.w));
    }
  }
  if (t < 128) *(uint4*)(ul + t * 8) = pu1;
  int m_next = idx[(size_t)((tile + 1) * 8 + rn) * K_ + kk];

  float sacc[4] = {0.f,0.f,0.f,0.f}, sacc2[4] = {0.f,0.f,0.f,0.f};
#pragma unroll
  for (int ti = 0; ti < 4; ++ti) {
    __syncthreads();   // staging (ul/Al writers) done; prev MFMA readers done
    { // stage A: a1[r][c] = relu((u+v)*A1 + B1) -> bf16, swizzled LDS
      const unsigned short* ulp = ul + rn * 128 + ch;   // wave-uniform row: broadcast
#pragma unroll
      for (int jj = 0; jj < 4; ++jj) {
        uint4 uu = *(const uint4*)(ulp + jj * 8);
        uint4 vv = PV[jj];
        const float* Ap = abl + ch + jj * 8;
        const float* Bp = abl + 128 + ch + jj * 8;
        float h0 = fmaxf(fmaf(bfl(uu.x) + bfl(vv.x), Ap[0], Bp[0]), 0.f);
        float h1 = fmaxf(fmaf(bfh(uu.x) + bfh(vv.x), Ap[1], Bp[1]), 0.f);
        float h2 = fmaxf(fmaf(bfl(uu.y) + bfl(vv.y), Ap[2], Bp[2]), 0.f);
        float h3 = fmaxf(fmaf(bfh(uu.y) + bfh(vv.y), Ap[3], Bp[3]), 0.f);
        float h4 = fmaxf(fmaf(bfl(uu.z) + bfl(vv.z), Ap[4], Bp[4]), 0.f);
        float h5 = fmaxf(fmaf(bfh(uu.z) + bfh(vv.z), Ap[5], Bp[5]), 0.f);
        float h6 = fmaxf(fmaf(bfl(uu.w) + bfl(vv.w), Ap[6], Bp[6]), 0.f);
        float h7 = fmaxf(fmaf(bfh(uu.w) + bfh(vv.w), Ap[7], Bp[7]), 0.f);
        *(uint4*)(Al + SWZ(r, r * 256 + (ch + jj * 8) * 2)) =
            make_uint4(pack2(h0,h1), pack2(h2,h3), pack2(h4,h5), pack2(h6,h7));
      }
    }
    __syncthreads();
    // prefetch next tile (loads in flight during MFMA + epilogue)
    if (ti < 3) {
      const int nn = (tile + 1) * 8 + rn;
      const unsigned short* vp = v + (((size_t)(nn >> 12) << 12) + m_next) * O_ + ch;
#pragma unroll
      for (int jj = 0; jj < 4; ++jj) PV[jj] = *(const uint4*)(vp + jj * 8);
      if (t < 128) pu1 = *(const uint4*)(u + (size_t)(tile + 1) * 1024 + t * 8);
    }
    if (ti < 2) m_next = idx[(size_t)((tile + 2) * 8 + rn) * K_ + kk];
    // MFMA: wave tile 32x64, 2x4 fragments x 4 k-steps
    f32x4 acc[2][4];
    f32x4 zero = {0.f, 0.f, 0.f, 0.f};
#pragma unroll
    for (int mi = 0; mi < 2; ++mi)
#pragma unroll
      for (int ni = 0; ni < 4; ++ni) acc[mi][ni] = zero;
#pragma unroll
    for (int ks = 0; ks < 4; ++ks) {
      const int cb = ks * 64 + kg * 16;
      s16x8 af[2], bf[4];
#pragma unroll
      for (int i = 0; i < 2; ++i) {
        const int ar = wm * 32 + i * 16 + r0;
        af[i] = *(const s16x8*)(Al + SWZ(ar, ar * 256 + cb));
      }
#pragma unroll
      for (int i = 0; i < 4; ++i) {
        const int br = wn * 64 + i * 16 + r0;
        bf[i] = *(const s16x8*)(Bl + SWZ(br, br * 256 + cb));
      }
#pragma unroll
      for (int mi = 0; mi < 2; ++mi)
#pragma unroll
        for (int ni = 0; ni < 4; ++ni)
          acc[mi][ni] = __builtin_amdgcn_mfma_f32_16x16x32_bf16(af[mi], bf[ni], acc[mi][ni], 0, 0, 0);
    }
    // write next tile's u rows (loads above have MFMA-time to land)
    if (ti < 3 && t < 128) *(uint4*)(ul + t * 8) = pu1;
    // epilogue: per-(n,o) max/min over the 16 k-rows + column sum/sumsq partials.
    // C/D layout: col = lane&15, row = kg*4 + i; fragment rows = one n's 16 neighbors.
#pragma unroll
    for (int ni = 0; ni < 4; ++ni) {
      const int col = wn * 64 + ni * 16 + r0;
#pragma unroll
      for (int mi = 0; mi < 2; ++mi) {
        float a0 = acc[mi][ni][0], a1 = acc[mi][ni][1];
        float a2 = acc[mi][ni][2], a3 = acc[mi][ni][3];
        float mx = fmaxf(fmaxf(a0, a1), fmaxf(a2, a3));
        float mn = fminf(fminf(a0, a1), fminf(a2, a3));
        mx = fmaxf(mx, __shfl_xor(mx, 16));
        mx = fmaxf(mx, __shfl_xor(mx, 32));
        mn = fminf(mn, __shfl_xor(mn, 16));
        mn = fminf(mn, __shfl_xor(mn, 32));
        if (lane < 16)
          hmm[(size_t)(tile * 8 + wm * 2 + mi) * O_ + col] = pack2(mx, mn);
        sacc[ni] += (a0 + a1) + (a2 + a3);
        sacc2[ni] += fmaf(a0, a0, fmaf(a1, a1, fmaf(a2, a2, a3 * a3)));
      }
    }
    ++tile;
  }
  // column sums -> atomics (once per block)
#pragma unroll
  for (int ni = 0; ni < 4; ++ni) {
    float s = sacc[ni], s2 = sacc2[ni];
    s += __shfl_xor(s, 16);  s += __shfl_xor(s, 32);
    s2 += __shfl_xor(s2, 16); s2 += __shfl_xor(s2, 32);
    if (lane < 16) { cred[w][ni * 16 + r0][0] = s; cred[w][ni * 16 + r0][1] = s2; }
  }
  __syncthreads();
  if (t < 128) {
    const int o = t, wn0 = o >> 6, cl = o & 63;
    float s = 0.f, s2 = 0.f;
#pragma unroll
    for (int g = 0; g < 4; ++g) {
      s += cred[g * 2 + wn0][cl][0];
      s2 += cred[g * 2 + wn0][cl][1];
    }
    atomicAdd(&stats2g[o], s);
    atomicAdd(&stats2g[O_ + o], s2);
  }
}

// ---------------------------------------------------------------- finalize: BN2+ReLU+select
__global__ __launch_bounds__(256) void finalize_kernel(const uint32_t* __restrict__ hmm,
        const float* __restrict__ stats2g, const float* __restrict__ g2,
        const float* __restrict__ b2, float* __restrict__ out) {
  __shared__ float Af[128], Bf[128];
  const int t = threadIdx.x;
  if (t < 128) {
    const float inv = 1.0f / (float)ROWS_;
    float s = stats2g[t], s2 = stats2g[O_ + t];
    float mean = s * inv;
    float var = fmaf(-mean, mean, s2 * inv);
    float A = g2[t] * rsqrtf(var + EPS_);
    Af[t] = A;
    Bf[t] = fmaf(-mean, A, b2[t]);
  }
  __syncthreads();
#pragma unroll
  for (int rep = 0; rep < 2; ++rep) {
    const int f4 = blockIdx.x * 512 + rep * 256 + t;   // uint4 index, 524288 total
    uint4 p = ((const uint4*)hmm)[f4];
    const int c = (f4 & 31) * 4;
    float4 o4;
    { float A = Af[c+0], Bb = Bf[c+0]; float sel = (A >= 0.f) ? bfl(p.x) : bfh(p.x);
      o4.x = fmaxf(fmaf(A, sel, Bb), 0.f); }
    { float A = Af[c+1], Bb = Bf[c+1]; float sel = (A >= 0.f) ? bfl(p.y) : bfh(p.y);
      o4.y = fmaxf(fmaf(A, sel, Bb), 0.f); }
    { float A = Af[c+2], Bb = Bf[c+2]; float sel = (A >= 0.f) ? bfl(p.z) : bfh(p.z);
      o4.z = fmaxf(fmaf(A, sel, Bb), 0.f); }
    { float A = Af[c+3], Bb = Bf[c+3]; float sel = (A >= 0.f) ? bfl(p.w) : bfh(p.w);
      o4.w = fmaxf(fmaf(A, sel, Bb), 0.f); }
    ((float4*)out)[f4] = o4;
  }
}

extern "C" void kernel_launch(void* const* d_in, const int* in_sizes, int n_in,
                              void* d_out, int out_size, void* d_ws, size_t ws_size,
                              hipStream_t stream) {
  const float* feats = (const float*)d_in[0];
  const float* xyz   = (const float*)d_in[1];
  const float* w1    = (const float*)d_in[2];
  const float* g1    = (const float*)d_in[3];
  const float* b1    = (const float*)d_in[4];
  const float* w2    = (const float*)d_in[5];
  const float* g2    = (const float*)d_in[6];
  const float* b2    = (const float*)d_in[7];
  float* out = (float*)d_out;

  char* ws = (char*)d_ws;                                        // ~17 MB used
  int*            idx     = (int*)(ws + 0);                      // 1 MB
  unsigned short* u       = (unsigned short*)(ws + (1ull << 20));  // 4 MB bf16
  unsigned short* v       = (unsigned short*)(ws + (5ull << 20));  // 4 MB bf16
  uint32_t*       hmm     = (uint32_t*)(ws + (9ull << 20));        // 8 MB packed (mx|mn)
  float*          stats1g = (float*)(ws + (17ull << 20));          // 1 KB
  float*          stats2g = (float*)(ws + (17ull << 20) + 4096);   // 1 KB

  knn_kernel<<<256, 1024, 0, stream>>>(xyz, idx);
  uv_kernel<<<256, 256, 0, stream>>>(feats, w1, u, v, stats1g, stats2g);
  stats1_kernel<<<512, 256, 0, stream>>>(u, v, idx, stats1g);
  gemm2_kernel<<<512, 512, 0, stream>>>(u, v, idx, stats1g, g1, b1, w2, stats2g, hmm);
  finalize_kernel<<<1024, 256, 0, stream>>>(hmm, stats2g, g2, b2, out);
}

// Round 7
// 208.963 us; speedup vs baseline: 1.4007x; 1.0587x over previous
//
#include <hip/hip_runtime.h>
#include <hip/hip_bf16.h>
#include <stdint.h>

// LocalAgg pipeline: KNN -> (factored) edge MLP -> BN+ReLU -> MLP -> BN+ReLU -> max over k.
// B=4 N=4096 C=64 O=128 K=16. Output FLOAT32 (B,N,O).
//
// 5 dispatches: knn, uv (bf16 u,v + stat zeroing + w2->bf16), stats1, gemm2 (single
// pass: hmax/hmin + BN2 stats), finalize (BN2+ReLU via monotone trick).
//
// KNN v4: |p|^2 staged in pts.w (4-op distance), per-wave top-10 (M1), merge at 20
// (M2) with round-1 publishing only the 10 real slots, 20-candidate exact-f64
// rank-select. Margins: top-15 item missing its chunk's top-10 needs 10 of its <=14
// betters in one 1/16 chunk (P~1e-9); escaping the merged top-20 needs >=6
// truncation-bucket collisions (P negligible; 16 would need only 2 -> unsafe).

#define B_ 4
#define N_ 4096
#define C_ 64
#define O_ 128
#define K_ 16
#define NQ_ (B_*N_)      // 16384
#define ROWS_ (NQ_*K_)   // 262144
#define EPS_ 1e-5f
#define M1_ 10           // knn per-wave list
#define M2_ 20           // knn merged candidate buffer

typedef float f32x4 __attribute__((ext_vector_type(4)));
typedef short s16x8 __attribute__((ext_vector_type(8)));

__device__ __forceinline__ unsigned short f2bf(float f) {
  union { float f; uint32_t u; } x; x.f = f;
  uint32_t r = x.u + 0x7FFFu + ((x.u >> 16) & 1u);
  return (unsigned short)(r >> 16);
}
__device__ __forceinline__ uint32_t pack2(float a, float b) {
  return (uint32_t)f2bf(a) | ((uint32_t)f2bf(b) << 16);
}
__device__ __forceinline__ float bfl(uint32_t x) { return __uint_as_float(x << 16); }
__device__ __forceinline__ float bfh(uint32_t x) { return __uint_as_float(x & 0xFFFF0000u); }

// ---------------------------------------------------------------- KNN v4
template<bool SELF>
__device__ __forceinline__ void knn_scan(const float4* pts, int j0, int jq,
                                         float nx, float ny, float nz, float qw,
                                         float* lst) {
#pragma unroll 4
  for (int j = j0; j < j0 + N_/16; ++j) {    // wave-uniform j -> LDS broadcast
    float4 P = pts[j];                        // x,y,z,|p|^2
    // d2 = |q|^2+|p|^2-2q.p (matches np's formula form; errors ~1e-6 << gaps,
    // absorbed by the 20-deep refine margin)
    float d2 = fmaf(P.z, nz, fmaf(P.y, ny, fmaf(P.x, nx, P.w + qw)));
    uint32_t kb = (__float_as_uint(d2) & 0xFFFFF000u) | (uint32_t)j;
    float k = __uint_as_float(kb);
    if (SELF) k = (j == jq) ? 1e30f : k;      // self: d2~0 key would be denormal
#pragma unroll
    for (int s = M1_-1; s >= 1; --s)          // branchless sorted-insert
      lst[s] = __builtin_amdgcn_fmed3f(lst[s-1], lst[s], k);
    lst[0] = fminf(lst[0], k);
  }
}

// 256 blocks x 1024 threads. Block = 64 queries (one per lane); 16 waves each scan a
// 256-candidate chunk keeping top-10; merge tree at 20; wave 0 exact-f64 refine.
__global__ __launch_bounds__(1024) void knn_kernel(const float* __restrict__ xyz,
                                                   int* __restrict__ idx_out) {
  __shared__ float4 pts[N_];                  // 64 KiB: x,y,z,|p|^2
  __shared__ float mbuf[8 * 64 * (M2_+1)];    // 42 KiB merge rows, stride 21
  const int t = threadIdx.x;
  const int lane = t & 63;
  const int w = t >> 6;
  const int qbase = blockIdx.x * 64;          // never straddles a batch
  const float* xb = xyz + (size_t)(qbase >> 12) * N_ * 3;
  for (int i = t; i < N_; i += 1024) {
    float x = xb[i*3+0], y = xb[i*3+1], z = xb[i*3+2];
    pts[i] = make_float4(x, y, z, fmaf(z, z, fmaf(y, y, x * x)));
  }
  __syncthreads();
  const int q0 = qbase & (N_-1);
  const int jq = q0 + lane;                   // this lane's query (local index)
  const float4 Q = pts[jq];
  float lst[M2_];
#pragma unroll
  for (int s = 0; s < M2_; ++s) lst[s] = 1e30f;   // slots [M1_,M2_) stay sentinel
  const int j0 = w * (N_/16);
  if (w == (q0 >> 8)) knn_scan<true >(pts, j0, jq, -2.f*Q.x, -2.f*Q.y, -2.f*Q.z, Q.w, lst);
  else                knn_scan<false>(pts, j0, jq, -2.f*Q.x, -2.f*Q.y, -2.f*Q.z, Q.w, lst);
  // merge tree; round 1 moves only the 10 real slots, later rounds all 20.
  for (int half = 8; half >= 1; half >>= 1) {
    const int cnt = (half == 8) ? M1_ : M2_;
    __syncthreads();
    if (w >= half && w < 2*half) {
      float* dst = mbuf + ((w - half) * 64 + lane) * (M2_+1);
      for (int s = 0; s < cnt; ++s) dst[s] = lst[s];
    }
    __syncthreads();
    if (w < half) {
      const float* src = mbuf + ((size_t)w * 64 + lane) * (M2_+1);
      for (int s = 0; s < cnt; ++s) {
        float k = src[s];
        if (!(k < lst[M2_-1])) break;         // src sorted ascending
#pragma unroll
        for (int s2 = M2_-1; s2 >= 1; --s2)
          lst[s2] = __builtin_amdgcn_fmed3f(lst[s2-1], lst[s2], k);
        lst[0] = fminf(lst[0], k);
      }
    }
  }
  // refine: exact f64 difference-form keys (matches np's f64 ordering to ~1e-15)
  // for the 20 survivors; rank-count -> top-15 set (+self at slot 0).
  if (w == 0) {
    const double qx = (double)Q.x, qy = (double)Q.y, qz = (double)Q.z;
    double dk[M2_]; int jj[M2_]; int rk[M2_];
#pragma unroll
    for (int s = 0; s < M2_; ++s) {
      int j = (int)(__float_as_uint(lst[s]) & 0xFFFu);
      jj[s] = j;
      float4 P = pts[j];
      double dx = (double)P.x - qx, dy = (double)P.y - qy, dz = (double)P.z - qz;
      double d2 = fma(dz, dz, fma(dy, dy, dx * dx));
      dk[s] = __longlong_as_double(
          (__double_as_longlong(d2) & ~0xFFFLL) | (long long)j);
      rk[s] = 0;
    }
#pragma unroll
    for (int a = 0; a < M2_; ++a)
#pragma unroll
      for (int c = a + 1; c < M2_; ++c) {
        bool lt = dk[a] < dk[c];              // keys distinct (idx packed)
        rk[c] += lt ? 1 : 0;
        rk[a] += lt ? 0 : 1;
      }
    int* op = idx_out + (size_t)(qbase + lane) * K_;
    op[0] = jq;                               // self: always reference rank 0
#pragma unroll
    for (int s = 0; s < M2_; ++s)
      if (rk[s] < K_-1) op[1 + rk[s]] = jj[s];
  }
}

// ---------------------------------------------------------------- u,v = feats @ {wA,wB}^T (bf16 out)
// Blocks 0-255: u,v tiles (block 0 also zeroes stats). Blocks 256-319: w2 -> bf16.
__global__ __launch_bounds__(256) void uv_kernel(const float* __restrict__ feats,
                                                 const float* __restrict__ w1,
                                                 unsigned short* __restrict__ u,
                                                 unsigned short* __restrict__ v,
                                                 const float* __restrict__ w2,
                                                 unsigned short* __restrict__ w2bf,
                                                 float* __restrict__ stats1g,
                                                 float* __restrict__ stats2g) {
  const int t = threadIdx.x;
  if (blockIdx.x >= 256) {
    const int e = (blockIdx.x - 256) * 256 + t;   // 64 blocks x 256 = 16384 = |w2|
    w2bf[e] = f2bf(w2[e]);
    return;
  }
  __shared__ float wl[O_][129];
  __shared__ float fl[64][65];
  if (blockIdx.x == 0) { stats1g[t] = 0.f; stats2g[t] = 0.f; }
  for (int e = t; e < O_*128; e += 256) wl[e >> 7][e & 127] = w1[e];
  const int rbase = blockIdx.x * 64;
  for (int e = t; e < 64*C_; e += 256)
    fl[e >> 6][e & 63] = feats[(size_t)(rbase + (e >> 6)) * C_ + (e & 63)];
  __syncthreads();
  const int o = t & 127, rh = t >> 7;
  for (int r = rh; r < 64; r += 2) {
    float au = 0.f, av = 0.f;
#pragma unroll
    for (int c = 0; c < C_; ++c) {
      float f = fl[r][c];
      float wa = wl[o][c], wb = wl[o][C_ + c];
      au = fmaf(f, wa - wb, au);
      av = fmaf(f, wb, av);
    }
    size_t off = (size_t)(rbase + r) * O_ + o;
    u[off] = f2bf(au); v[off] = f2bf(av);
  }
}

// ---------------------------------------------------------------- BN1 stats over h1=u+v[idx]
__global__ __launch_bounds__(256) void stats1_kernel(const unsigned short* __restrict__ u,
                                                     const unsigned short* __restrict__ v,
                                                     const int* __restrict__ idx,
                                                     float* __restrict__ stats) {
  __shared__ float red[16][128][2];   // 16 KB
  const int t = threadIdx.x;
  const int bid = blockIdx.x;
  const int blk = (bid & 7) * 64 + (bid >> 3);   // XCD i -> rows [i*2048,(i+1)*2048)
  const int o8 = (t & 15) * 8, rg = t >> 4;      // 16 lanes x 16 row-groups
  const int rbase = blk * 32;
  float s[8], q[8];
#pragma unroll
  for (int i = 0; i < 8; ++i) { s[i] = 0.f; q[i] = 0.f; }
#pragma unroll
  for (int r = rg; r < 32; r += 16) {            // 2 rows per thread
    const int R = rbase + r;
    const int bb = R >> 12;
    uint4 uu = *(const uint4*)(u + (size_t)R * O_ + o8);
    float uf[8] = { bfl(uu.x), bfh(uu.x), bfl(uu.y), bfh(uu.y),
                    bfl(uu.z), bfh(uu.z), bfl(uu.w), bfh(uu.w) };
    int4 i0 = *(const int4*)(idx + (size_t)R * K_);
    int4 i1 = *(const int4*)(idx + (size_t)R * K_ + 4);
    int4 i2 = *(const int4*)(idx + (size_t)R * K_ + 8);
    int4 i3 = *(const int4*)(idx + (size_t)R * K_ + 12);
    int mi[16] = { i0.x,i0.y,i0.z,i0.w, i1.x,i1.y,i1.z,i1.w,
                   i2.x,i2.y,i2.z,i2.w, i3.x,i3.y,i3.z,i3.w };
    const unsigned short* vb = v + ((size_t)bb << 12) * O_ + o8;
#pragma unroll
    for (int k = 0; k < K_; ++k) {
      uint4 vv = *(const uint4*)(vb + (size_t)mi[k] * O_);
      float h;
      h = uf[0] + bfl(vv.x); s[0] += h; q[0] = fmaf(h, h, q[0]);
      h = uf[1] + bfh(vv.x); s[1] += h; q[1] = fmaf(h, h, q[1]);
      h = uf[2] + bfl(vv.y); s[2] += h; q[2] = fmaf(h, h, q[2]);
      h = uf[3] + bfh(vv.y); s[3] += h; q[3] = fmaf(h, h, q[3]);
      h = uf[4] + bfl(vv.z); s[4] += h; q[4] = fmaf(h, h, q[4]);
      h = uf[5] + bfh(vv.z); s[5] += h; q[5] = fmaf(h, h, q[5]);
      h = uf[6] + bfl(vv.w); s[6] += h; q[6] = fmaf(h, h, q[6]);
      h = uf[7] + bfh(vv.w); s[7] += h; q[7] = fmaf(h, h, q[7]);
    }
  }
#pragma unroll
  for (int i = 0; i < 8; ++i) { red[rg][o8 + i][0] = s[i]; red[rg][o8 + i][1] = q[i]; }
  __syncthreads();
  if (t < 128) {
    float ss = 0.f, qq = 0.f;
#pragma unroll
    for (int g = 0; g < 16; ++g) { ss += red[g][t][0]; qq += red[g][t][1]; }
    atomicAdd(&stats[t], ss);
    atomicAdd(&stats[O_ + t], qq);
  }
}

// ---------------------------------------------------------------- gemm2 (single pass)
// 512 blocks x 512 threads (8 waves, 4x2), 2 blocks/CU. XCD-contiguous tile swizzle.
// 4 row-tiles/block, reg-staged prefetch. (512,2): VGPR cap 256, no spill.
#define SWZ(row, byteoff) ((byteoff) ^ (((row) & 7) << 4))

__global__ __launch_bounds__(512, 2) void gemm2_kernel(
    const unsigned short* __restrict__ u, const unsigned short* __restrict__ v,
    const int* __restrict__ idx,
    const float* __restrict__ stats1g, const float* __restrict__ g1, const float* __restrict__ b1,
    const unsigned short* __restrict__ w2bf,
    float* __restrict__ stats2g, uint32_t* __restrict__ hmm) {
  __shared__ unsigned char Al[128 * 256];   // a1 tile bf16, swizzled
  __shared__ unsigned char Bl[128 * 256];   // w2 tile bf16, swizzled
  __shared__ unsigned short ul[1024];       // 8 u-rows (bf16) of current tile
  __shared__ float abl[256];                // BN1 affine A|B
  __shared__ float cred[8][64][2];          // end-of-kernel column reduce
  const int t = threadIdx.x;
  const int bid = blockIdx.x;
  const int blk = (bid & 7) * 64 + (bid >> 3);   // XCD i -> tiles of half a batch
  const float inv = 1.0f / (float)ROWS_;
  const int r = t >> 2, q = t & 3, ch = q * 32;
  const int rn = r >> 4, kk = r & 15;       // tile-local n, neighbor slot
  const int w = t >> 6, lane = t & 63;
  const int wm = w >> 1, wn = w & 1;        // 4x2 wave grid, wave tile 32x64
  const int r0 = lane & 15, kg = lane >> 4;

  int tile = blk * 4;
  // prologue: idx -> v prefetch (tile 0), u rows (tile 0), BN1 affine, stage B
  int m_cur = idx[(size_t)(tile * 8 + rn) * K_ + kk];
  uint4 PV[4];
  {
    const int n0 = tile * 8 + rn;
    const unsigned short* vp = v + (((size_t)(n0 >> 12) << 12) + m_cur) * O_ + ch;
#pragma unroll
    for (int jj = 0; jj < 4; ++jj) PV[jj] = *(const uint4*)(vp + jj * 8);
  }
  uint4 pu1;
  if (t < 128) {
    pu1 = *(const uint4*)(u + (size_t)tile * 1024 + t * 8);
    float s = stats1g[t], s2 = stats1g[O_ + t];
    float mean = s * inv;
    float var = fmaf(-mean, mean, s2 * inv);
    float A = g1[t] * rsqrtf(var + EPS_);
    abl[t] = A;
    abl[O_ + t] = fmaf(-mean, A, b1[t]);
  }
  { // stage B: w2 (pre-converted bf16) row o, 32 cols, swizzled
    const int o = t >> 2, c0 = q * 32;
    const unsigned short* src = w2bf + o * 128 + c0;
#pragma unroll
    for (int jj = 0; jj < 4; ++jj) {
      uint4 val = *(const uint4*)(src + jj * 8);
      *(uint4*)(Bl + SWZ(o, o * 256 + (c0 + jj * 8) * 2)) = val;
    }
  }
  if (t < 128) *(uint4*)(ul + t * 8) = pu1;
  int m_next = idx[(size_t)((tile + 1) * 8 + rn) * K_ + kk];

  float sacc[4] = {0.f,0.f,0.f,0.f}, sacc2[4] = {0.f,0.f,0.f,0.f};
#pragma unroll
  for (int ti = 0; ti < 4; ++ti) {
    __syncthreads();   // staging (ul/Al writers) done; prev MFMA readers done
    { // stage A: a1[r][c] = relu((u+v)*A1 + B1) -> bf16, swizzled LDS
      const unsigned short* ulp = ul + rn * 128 + ch;   // wave-uniform row: broadcast
#pragma unroll
      for (int jj = 0; jj < 4; ++jj) {
        uint4 uu = *(const uint4*)(ulp + jj * 8);
        uint4 vv = PV[jj];
        const float* Ap = abl + ch + jj * 8;
        const float* Bp = abl + 128 + ch + jj * 8;
        float h0 = fmaxf(fmaf(bfl(uu.x) + bfl(vv.x), Ap[0], Bp[0]), 0.f);
        float h1 = fmaxf(fmaf(bfh(uu.x) + bfh(vv.x), Ap[1], Bp[1]), 0.f);
        float h2 = fmaxf(fmaf(bfl(uu.y) + bfl(vv.y), Ap[2], Bp[2]), 0.f);
        float h3 = fmaxf(fmaf(bfh(uu.y) + bfh(vv.y), Ap[3], Bp[3]), 0.f);
        float h4 = fmaxf(fmaf(bfl(uu.z) + bfl(vv.z), Ap[4], Bp[4]), 0.f);
        float h5 = fmaxf(fmaf(bfh(uu.z) + bfh(vv.z), Ap[5], Bp[5]), 0.f);
        float h6 = fmaxf(fmaf(bfl(uu.w) + bfl(vv.w), Ap[6], Bp[6]), 0.f);
        float h7 = fmaxf(fmaf(bfh(uu.w) + bfh(vv.w), Ap[7], Bp[7]), 0.f);
        *(uint4*)(Al + SWZ(r, r * 256 + (ch + jj * 8) * 2)) =
            make_uint4(pack2(h0,h1), pack2(h2,h3), pack2(h4,h5), pack2(h6,h7));
      }
    }
    __syncthreads();
    // prefetch next tile (loads in flight during MFMA + epilogue)
    if (ti < 3) {
      const int nn = (tile + 1) * 8 + rn;
      const unsigned short* vp = v + (((size_t)(nn >> 12) << 12) + m_next) * O_ + ch;
#pragma unroll
      for (int jj = 0; jj < 4; ++jj) PV[jj] = *(const uint4*)(vp + jj * 8);
      if (t < 128) pu1 = *(const uint4*)(u + (size_t)(tile + 1) * 1024 + t * 8);
    }
    if (ti < 2) m_next = idx[(size_t)((tile + 2) * 8 + rn) * K_ + kk];
    // MFMA: wave tile 32x64, 2x4 fragments x 4 k-steps
    f32x4 acc[2][4];
    f32x4 zero = {0.f, 0.f, 0.f, 0.f};
#pragma unroll
    for (int mi = 0; mi < 2; ++mi)
#pragma unroll
      for (int ni = 0; ni < 4; ++ni) acc[mi][ni] = zero;
#pragma unroll
    for (int ks = 0; ks < 4; ++ks) {
      const int cb = ks * 64 + kg * 16;
      s16x8 af[2], bf[4];
#pragma unroll
      for (int i = 0; i < 2; ++i) {
        const int ar = wm * 32 + i * 16 + r0;
        af[i] = *(const s16x8*)(Al + SWZ(ar, ar * 256 + cb));
      }
#pragma unroll
      for (int i = 0; i < 4; ++i) {
        const int br = wn * 64 + i * 16 + r0;
        bf[i] = *(const s16x8*)(Bl + SWZ(br, br * 256 + cb));
      }
#pragma unroll
      for (int mi = 0; mi < 2; ++mi)
#pragma unroll
        for (int ni = 0; ni < 4; ++ni)
          acc[mi][ni] = __builtin_amdgcn_mfma_f32_16x16x32_bf16(af[mi], bf[ni], acc[mi][ni], 0, 0, 0);
    }
    // write next tile's u rows (loads above have MFMA-time to land)
    if (ti < 3 && t < 128) *(uint4*)(ul + t * 8) = pu1;
    // epilogue: per-(n,o) max/min over the 16 k-rows + column sum/sumsq partials.
#pragma unroll
    for (int ni = 0; ni < 4; ++ni) {
      const int col = wn * 64 + ni * 16 + r0;
#pragma unroll
      for (int mi = 0; mi < 2; ++mi) {
        float a0 = acc[mi][ni][0], a1 = acc[mi][ni][1];
        float a2 = acc[mi][ni][2], a3 = acc[mi][ni][3];
        float mx = fmaxf(fmaxf(a0, a1), fmaxf(a2, a3));
        float mn = fminf(fminf(a0, a1), fminf(a2, a3));
        mx = fmaxf(mx, __shfl_xor(mx, 16));
        mx = fmaxf(mx, __shfl_xor(mx, 32));
        mn = fminf(mn, __shfl_xor(mn, 16));
        mn = fminf(mn, __shfl_xor(mn, 32));
        if (lane < 16)
          hmm[(size_t)(tile * 8 + wm * 2 + mi) * O_ + col] = pack2(mx, mn);
        sacc[ni] += (a0 + a1) + (a2 + a3);
        sacc2[ni] += fmaf(a0, a0, fmaf(a1, a1, fmaf(a2, a2, a3 * a3)));
      }
    }
    ++tile;
  }
  // column sums -> atomics (once per block)
#pragma unroll
  for (int ni = 0; ni < 4; ++ni) {
    float s = sacc[ni], s2 = sacc2[ni];
    s += __shfl_xor(s, 16);  s += __shfl_xor(s, 32);
    s2 += __shfl_xor(s2, 16); s2 += __shfl_xor(s2, 32);
    if (lane < 16) { cred[w][ni * 16 + r0][0] = s; cred[w][ni * 16 + r0][1] = s2; }
  }
  __syncthreads();
  if (t < 128) {
    const int o = t, wn0 = o >> 6, cl = o & 63;
    float s = 0.f, s2 = 0.f;
#pragma unroll
    for (int g = 0; g < 4; ++g) {
      s += cred[g * 2 + wn0][cl][0];
      s2 += cred[g * 2 + wn0][cl][1];
    }
    atomicAdd(&stats2g[o], s);
    atomicAdd(&stats2g[O_ + o], s2);
  }
}

// ---------------------------------------------------------------- finalize: BN2+ReLU+select
__global__ __launch_bounds__(256) void finalize_kernel(const uint32_t* __restrict__ hmm,
        const float* __restrict__ stats2g, const float* __restrict__ g2,
        const float* __restrict__ b2, float* __restrict__ out) {
  __shared__ float Af[128], Bf[128];
  const int t = threadIdx.x;
  if (t < 128) {
    const float inv = 1.0f / (float)ROWS_;
    float s = stats2g[t], s2 = stats2g[O_ + t];
    float mean = s * inv;
    float var = fmaf(-mean, mean, s2 * inv);
    float A = g2[t] * rsqrtf(var + EPS_);
    Af[t] = A;
    Bf[t] = fmaf(-mean, A, b2[t]);
  }
  __syncthreads();
#pragma unroll
  for (int rep = 0; rep < 2; ++rep) {
    const int f4 = blockIdx.x * 512 + rep * 256 + t;   // uint4 index, 524288 total
    uint4 p = ((const uint4*)hmm)[f4];
    const int c = (f4 & 31) * 4;
    float4 o4;
    { float A = Af[c+0], Bb = Bf[c+0]; float sel = (A >= 0.f) ? bfl(p.x) : bfh(p.x);
      o4.x = fmaxf(fmaf(A, sel, Bb), 0.f); }
    { float A = Af[c+1], Bb = Bf[c+1]; float sel = (A >= 0.f) ? bfl(p.y) : bfh(p.y);
      o4.y = fmaxf(fmaf(A, sel, Bb), 0.f); }
    { float A = Af[c+2], Bb = Bf[c+2]; float sel = (A >= 0.f) ? bfl(p.z) : bfh(p.z);
      o4.z = fmaxf(fmaf(A, sel, Bb), 0.f); }
    { float A = Af[c+3], Bb = Bf[c+3]; float sel = (A >= 0.f) ? bfl(p.w) : bfh(p.w);
      o4.w = fmaxf(fmaf(A, sel, Bb), 0.f); }
    ((float4*)out)[f4] = o4;
  }
}

extern "C" void kernel_launch(void* const* d_in, const int* in_sizes, int n_in,
                              void* d_out, int out_size, void* d_ws, size_t ws_size,
                              hipStream_t stream) {
  const float* feats = (const float*)d_in[0];
  const float* xyz   = (const float*)d_in[1];
  const float* w1    = (const float*)d_in[2];
  const float* g1    = (const float*)d_in[3];
  const float* b1    = (const float*)d_in[4];
  const float* w2    = (const float*)d_in[5];
  const float* g2    = (const float*)d_in[6];
  const float* b2    = (const float*)d_in[7];
  float* out = (float*)d_out;

  char* ws = (char*)d_ws;                                          // ~17 MB used
  int*            idx     = (int*)(ws + 0);                        // 1 MB
  unsigned short* u       = (unsigned short*)(ws + (1ull << 20));  // 4 MB bf16
  unsigned short* v       = (unsigned short*)(ws + (5ull << 20));  // 4 MB bf16
  uint32_t*       hmm     = (uint32_t*)(ws + (9ull << 20));        // 8 MB packed (mx|mn)
  float*          stats1g = (float*)(ws + (17ull << 20));          // 1 KB
  float*          stats2g = (float*)(ws + (17ull << 20) + 4096);   // 1 KB
  unsigned short* w2bf    = (unsigned short*)(ws + (17ull << 20) + 8192);  // 32 KB

  knn_kernel<<<256, 1024, 0, stream>>>(xyz, idx);
  uv_kernel<<<320, 256, 0, stream>>>(feats, w1, u, v, w2, w2bf, stats1g, stats2g);
  stats1_kernel<<<512, 256, 0, stream>>>(u, v, idx, stats1g);
  gemm2_kernel<<<512, 512, 0, stream>>>(u, v, idx, stats1g, g1, b1, w2bf, stats2g, hmm);
  finalize_kernel<<<1024, 256, 0, stream>>>(hmm, stats2g, g2, b2, out);
}

// Round 8
// 175.292 us; speedup vs baseline: 1.6697x; 1.1921x over previous
//
#include <hip/hip_runtime.h>
#include <hip/hip_bf16.h>
#include <stdint.h>

// LocalAgg pipeline: KNN -> (factored) edge MLP -> BN+ReLU -> MLP -> BN+ReLU -> max over k.
// B=4 N=4096 C=64 O=128 K=16. Output FLOAT32 (B,N,O).
//
// 5 dispatches: knn, uv (MFMA: [u|v] = feats_bf16 @ [wa-wb|wb]^T, + stat zeroing +
// w2->bf16), stats1 (1-row/thread gather, 4-copy atomics), gemm2 (single pass:
// hmax/hmin + BN2 stats), finalize (BN2+ReLU via monotone max/min trick).
//
// R8: uv scalar->MFMA (was 1 wave/SIMD latency-bound scalar GEMM); stats1 grid 512->
// 1024 with one gather-row per thread (16 independent v-gathers in flight) and 4
// shadow stat copies (atomic chain 1024->256 per address).

#define B_ 4
#define N_ 4096
#define C_ 64
#define O_ 128
#define K_ 16
#define NQ_ (B_*N_)      // 16384
#define ROWS_ (NQ_*K_)   // 262144
#define EPS_ 1e-5f
#define M1_ 10           // knn per-wave list
#define M2_ 20           // knn merged candidate buffer

typedef float f32x4 __attribute__((ext_vector_type(4)));
typedef short s16x8 __attribute__((ext_vector_type(8)));

__device__ __forceinline__ unsigned short f2bf(float f) {
  union { float f; uint32_t u; } x; x.f = f;
  uint32_t r = x.u + 0x7FFFu + ((x.u >> 16) & 1u);
  return (unsigned short)(r >> 16);
}
__device__ __forceinline__ uint32_t pack2(float a, float b) {
  return (uint32_t)f2bf(a) | ((uint32_t)f2bf(b) << 16);
}
__device__ __forceinline__ float bfl(uint32_t x) { return __uint_as_float(x << 16); }
__device__ __forceinline__ float bfh(uint32_t x) { return __uint_as_float(x & 0xFFFF0000u); }

#define SWZ(row, byteoff) ((byteoff) ^ (((row) & 7) << 4))

// ---------------------------------------------------------------- KNN v4 (unchanged)
template<bool SELF>
__device__ __forceinline__ void knn_scan(const float4* pts, int j0, int jq,
                                         float nx, float ny, float nz, float qw,
                                         float* lst) {
#pragma unroll 4
  for (int j = j0; j < j0 + N_/16; ++j) {    // wave-uniform j -> LDS broadcast
    float4 P = pts[j];                        // x,y,z,|p|^2
    float d2 = fmaf(P.z, nz, fmaf(P.y, ny, fmaf(P.x, nx, P.w + qw)));
    uint32_t kb = (__float_as_uint(d2) & 0xFFFFF000u) | (uint32_t)j;
    float k = __uint_as_float(kb);
    if (SELF) k = (j == jq) ? 1e30f : k;      // self: d2~0 key would be denormal
#pragma unroll
    for (int s = M1_-1; s >= 1; --s)          // branchless sorted-insert
      lst[s] = __builtin_amdgcn_fmed3f(lst[s-1], lst[s], k);
    lst[0] = fminf(lst[0], k);
  }
}

__global__ __launch_bounds__(1024) void knn_kernel(const float* __restrict__ xyz,
                                                   int* __restrict__ idx_out) {
  __shared__ float4 pts[N_];                  // 64 KiB: x,y,z,|p|^2
  __shared__ float mbuf[8 * 64 * (M2_+1)];    // 42 KiB merge rows, stride 21
  const int t = threadIdx.x;
  const int lane = t & 63;
  const int w = t >> 6;
  const int qbase = blockIdx.x * 64;          // never straddles a batch
  const float* xb = xyz + (size_t)(qbase >> 12) * N_ * 3;
  for (int i = t; i < N_; i += 1024) {
    float x = xb[i*3+0], y = xb[i*3+1], z = xb[i*3+2];
    pts[i] = make_float4(x, y, z, fmaf(z, z, fmaf(y, y, x * x)));
  }
  __syncthreads();
  const int q0 = qbase & (N_-1);
  const int jq = q0 + lane;                   // this lane's query (local index)
  const float4 Q = pts[jq];
  float lst[M2_];
#pragma unroll
  for (int s = 0; s < M2_; ++s) lst[s] = 1e30f;   // slots [M1_,M2_) stay sentinel
  const int j0 = w * (N_/16);
  if (w == (q0 >> 8)) knn_scan<true >(pts, j0, jq, -2.f*Q.x, -2.f*Q.y, -2.f*Q.z, Q.w, lst);
  else                knn_scan<false>(pts, j0, jq, -2.f*Q.x, -2.f*Q.y, -2.f*Q.z, Q.w, lst);
  // merge tree; round 1 moves only the 10 real slots, later rounds all 20.
  for (int half = 8; half >= 1; half >>= 1) {
    const int cnt = (half == 8) ? M1_ : M2_;
    __syncthreads();
    if (w >= half && w < 2*half) {
      float* dst = mbuf + ((w - half) * 64 + lane) * (M2_+1);
      for (int s = 0; s < cnt; ++s) dst[s] = lst[s];
    }
    __syncthreads();
    if (w < half) {
      const float* src = mbuf + ((size_t)w * 64 + lane) * (M2_+1);
      for (int s = 0; s < cnt; ++s) {
        float k = src[s];
        if (!(k < lst[M2_-1])) break;         // src sorted ascending
#pragma unroll
        for (int s2 = M2_-1; s2 >= 1; --s2)
          lst[s2] = __builtin_amdgcn_fmed3f(lst[s2-1], lst[s2], k);
        lst[0] = fminf(lst[0], k);
      }
    }
  }
  // refine: exact f64 difference-form keys (matches np's f64 ordering to ~1e-15)
  if (w == 0) {
    const double qx = (double)Q.x, qy = (double)Q.y, qz = (double)Q.z;
    double dk[M2_]; int jj[M2_]; int rk[M2_];
#pragma unroll
    for (int s = 0; s < M2_; ++s) {
      int j = (int)(__float_as_uint(lst[s]) & 0xFFFu);
      jj[s] = j;
      float4 P = pts[j];
      double dx = (double)P.x - qx, dy = (double)P.y - qy, dz = (double)P.z - qz;
      double d2 = fma(dz, dz, fma(dy, dy, dx * dx));
      dk[s] = __longlong_as_double(
          (__double_as_longlong(d2) & ~0xFFFLL) | (long long)j);
      rk[s] = 0;
    }
#pragma unroll
    for (int a = 0; a < M2_; ++a)
#pragma unroll
      for (int c = a + 1; c < M2_; ++c) {
        bool lt = dk[a] < dk[c];              // keys distinct (idx packed)
        rk[c] += lt ? 1 : 0;
        rk[a] += lt ? 0 : 1;
      }
    int* op = idx_out + (size_t)(qbase + lane) * K_;
    op[0] = jq;                               // self: always reference rank 0
#pragma unroll
    for (int s = 0; s < M2_; ++s)
      if (rk[s] < K_-1) op[1 + rk[s]] = jj[s];
  }
}

// ---------------------------------------------------------------- uv (MFMA)
// [u|v](16384 x 256) = feats_bf16 (16384 x 64) @ W'^T, W' = [wa-wb | wb] (256 x 64).
// 256 blocks x 256 thr (4 waves); block = 64 rows x 256 cols; wave = 64 x 64.
// Side duties: block0 zeroes stats (4-copy stats1g: 1024 + stats2g: 256);
// blocks 0-63 convert w2 -> bf16.
__global__ __launch_bounds__(256) void uv_kernel(const float* __restrict__ feats,
                                                 const float* __restrict__ w1,
                                                 unsigned short* __restrict__ u,
                                                 unsigned short* __restrict__ v,
                                                 const float* __restrict__ w2,
                                                 unsigned short* __restrict__ w2bf,
                                                 float* __restrict__ stats1g,
                                                 float* __restrict__ stats2g) {
  __shared__ unsigned char Wl[256 * 128];   // 32KB: 256 out-cols x 64 bf16, swizzled
  __shared__ unsigned char Fl[64 * 128];    // 8KB: 64 rows x 64 bf16, swizzled
  const int t = threadIdx.x;
  const int blk = blockIdx.x;
  if (blk == 0) {
    for (int e = t; e < 1024; e += 256) stats1g[e] = 0.f;
    stats2g[t] = 0.f;
  }
  if (blk < 64) {
    const int e = blk * 256 + t;            // 64*256 = 16384 = |w2|
    w2bf[e] = f2bf(w2[e]);
  }
  { // stage W': out-col t; cols<128: wa-wb row, cols>=128: wb row
    const int ow = t;
    if (ow < 128) {
      const float* wa = w1 + ow * 128;
      const float* wb = wa + 64;
#pragma unroll
      for (int g = 0; g < 8; ++g) {
        float4 a0 = *(const float4*)(wa + g*8);
        float4 a1 = *(const float4*)(wa + g*8 + 4);
        float4 b0 = *(const float4*)(wb + g*8);
        float4 b1 = *(const float4*)(wb + g*8 + 4);
        *(uint4*)(Wl + SWZ(ow, ow*128 + g*16)) =
            make_uint4(pack2(a0.x-b0.x, a0.y-b0.y), pack2(a0.z-b0.z, a0.w-b0.w),
                       pack2(a1.x-b1.x, a1.y-b1.y), pack2(a1.z-b1.z, a1.w-b1.w));
      }
    } else {
      const float* wb = w1 + (ow - 128) * 128 + 64;
#pragma unroll
      for (int g = 0; g < 8; ++g) {
        float4 a0 = *(const float4*)(wb + g*8);
        float4 a1 = *(const float4*)(wb + g*8 + 4);
        *(uint4*)(Wl + SWZ(ow, ow*128 + g*16)) =
            make_uint4(pack2(a0.x, a0.y), pack2(a0.z, a0.w),
                       pack2(a1.x, a1.y), pack2(a1.z, a1.w));
      }
    }
  }
  { // stage feats rows -> bf16
    const int row = t >> 2, q = t & 3;      // 16 ch per (row, q)
    const float* fp = feats + (size_t)(blk * 64 + row) * 64 + q * 16;
#pragma unroll
    for (int g = 0; g < 2; ++g) {
      float4 a = *(const float4*)(fp + g*8);
      float4 b = *(const float4*)(fp + g*8 + 4);
      *(uint4*)(Fl + SWZ(row, row*128 + q*32 + g*16)) =
          make_uint4(pack2(a.x,a.y), pack2(a.z,a.w), pack2(b.x,b.y), pack2(b.z,b.w));
    }
  }
  __syncthreads();
  const int w = t >> 6, lane = t & 63;      // w = col quarter
  const int r0 = lane & 15, kg = lane >> 4;
  f32x4 acc[4][4];
  f32x4 zero = {0.f, 0.f, 0.f, 0.f};
#pragma unroll
  for (int mi = 0; mi < 4; ++mi)
#pragma unroll
    for (int ni = 0; ni < 4; ++ni) acc[mi][ni] = zero;
#pragma unroll
  for (int ks = 0; ks < 2; ++ks) {
    const int cb = ks * 64 + kg * 16;       // byte: elem = ks*32 + kg*8
    s16x8 af[4], bf[4];
#pragma unroll
    for (int i = 0; i < 4; ++i) {
      const int ar = i * 16 + r0;
      af[i] = *(const s16x8*)(Fl + SWZ(ar, ar*128 + cb));
      const int br = w * 64 + i * 16 + r0;
      bf[i] = *(const s16x8*)(Wl + SWZ(br, br*128 + cb));
    }
#pragma unroll
    for (int mi = 0; mi < 4; ++mi)
#pragma unroll
      for (int ni = 0; ni < 4; ++ni)
        acc[mi][ni] = __builtin_amdgcn_mfma_f32_16x16x32_bf16(af[mi], bf[ni], acc[mi][ni], 0, 0, 0);
  }
  // C/D: col = lane&15, row = kg*4 + i. cols 0-127 -> u, 128-255 -> v (wave-uniform).
  const int rbase = blk * 64;
#pragma unroll
  for (int ni = 0; ni < 4; ++ni) {
    const int col = w * 64 + ni * 16 + r0;
    unsigned short* dst = (col < 128) ? (u + col) : (v + col - 128);
#pragma unroll
    for (int mi = 0; mi < 4; ++mi)
#pragma unroll
      for (int i = 0; i < 4; ++i) {
        const int row = rbase + mi * 16 + kg * 4 + i;
        dst[(size_t)row * O_] = f2bf(acc[mi][ni][i]);
      }
  }
}

// ---------------------------------------------------------------- BN1 stats over h1=u+v[idx]
// 1024 blocks x 256 thr; thread = one gather-row half-channel set: 16 independent
// v-gathers in flight. 4 shadow stat copies (bid&3) to cut atomic chains.
__global__ __launch_bounds__(256) void stats1_kernel(const unsigned short* __restrict__ u,
                                                     const unsigned short* __restrict__ v,
                                                     const int* __restrict__ idx,
                                                     float* __restrict__ stats) {
  __shared__ float red[16][128][2];   // 16 KB
  const int t = threadIdx.x;
  const int bid = blockIdx.x;
  const int blk = (bid & 7) * 128 + (bid >> 3);  // XCD i -> contiguous 1/8 of rows
  const int o8 = (t & 15) * 8, rg = t >> 4;      // 16 lanes x 16 rows
  const int R = blk * 16 + rg;
  const int bb = R >> 12;
  float s[8], q[8];
#pragma unroll
  for (int i = 0; i < 8; ++i) { s[i] = 0.f; q[i] = 0.f; }
  uint4 uu = *(const uint4*)(u + (size_t)R * O_ + o8);
  float uf[8] = { bfl(uu.x), bfh(uu.x), bfl(uu.y), bfh(uu.y),
                  bfl(uu.z), bfh(uu.z), bfl(uu.w), bfh(uu.w) };
  int4 i0 = *(const int4*)(idx + (size_t)R * K_);
  int4 i1 = *(const int4*)(idx + (size_t)R * K_ + 4);
  int4 i2 = *(const int4*)(idx + (size_t)R * K_ + 8);
  int4 i3 = *(const int4*)(idx + (size_t)R * K_ + 12);
  int mi[16] = { i0.x,i0.y,i0.z,i0.w, i1.x,i1.y,i1.z,i1.w,
                 i2.x,i2.y,i2.z,i2.w, i3.x,i3.y,i3.z,i3.w };
  const unsigned short* vb = v + ((size_t)bb << 12) * O_ + o8;
#pragma unroll
  for (int k = 0; k < K_; ++k) {
    uint4 vv = *(const uint4*)(vb + (size_t)mi[k] * O_);
    float h;
    h = uf[0] + bfl(vv.x); s[0] += h; q[0] = fmaf(h, h, q[0]);
    h = uf[1] + bfh(vv.x); s[1] += h; q[1] = fmaf(h, h, q[1]);
    h = uf[2] + bfl(vv.y); s[2] += h; q[2] = fmaf(h, h, q[2]);
    h = uf[3] + bfh(vv.y); s[3] += h; q[3] = fmaf(h, h, q[3]);
    h = uf[4] + bfl(vv.z); s[4] += h; q[4] = fmaf(h, h, q[4]);
    h = uf[5] + bfh(vv.z); s[5] += h; q[5] = fmaf(h, h, q[5]);
    h = uf[6] + bfl(vv.w); s[6] += h; q[6] = fmaf(h, h, q[6]);
    h = uf[7] + bfh(vv.w); s[7] += h; q[7] = fmaf(h, h, q[7]);
  }
#pragma unroll
  for (int i = 0; i < 8; ++i) { red[rg][o8 + i][0] = s[i]; red[rg][o8 + i][1] = q[i]; }
  __syncthreads();
  if (t < 128) {
    float ss = 0.f, qq = 0.f;
#pragma unroll
    for (int g = 0; g < 16; ++g) { ss += red[g][t][0]; qq += red[g][t][1]; }
    float* sc = stats + (bid & 3) * 256;
    atomicAdd(&sc[t], ss);
    atomicAdd(&sc[128 + t], qq);
  }
}

// ---------------------------------------------------------------- gemm2 (single pass)
__global__ __launch_bounds__(512, 2) void gemm2_kernel(
    const unsigned short* __restrict__ u, const unsigned short* __restrict__ v,
    const int* __restrict__ idx,
    const float* __restrict__ stats1g, const float* __restrict__ g1, const float* __restrict__ b1,
    const unsigned short* __restrict__ w2bf,
    float* __restrict__ stats2g, uint32_t* __restrict__ hmm) {
  __shared__ unsigned char Al[128 * 256];   // a1 tile bf16, swizzled
  __shared__ unsigned char Bl[128 * 256];   // w2 tile bf16, swizzled
  __shared__ unsigned short ul[1024];       // 8 u-rows (bf16) of current tile
  __shared__ float abl[256];                // BN1 affine A|B
  __shared__ float cred[8][64][2];          // end-of-kernel column reduce
  const int t = threadIdx.x;
  const int bid = blockIdx.x;
  const int blk = (bid & 7) * 64 + (bid >> 3);   // XCD i -> tiles of half a batch
  const float inv = 1.0f / (float)ROWS_;
  const int r = t >> 2, q = t & 3, ch = q * 32;
  const int rn = r >> 4, kk = r & 15;       // tile-local n, neighbor slot
  const int w = t >> 6, lane = t & 63;
  const int wm = w >> 1, wn = w & 1;        // 4x2 wave grid, wave tile 32x64
  const int r0 = lane & 15, kg = lane >> 4;

  int tile = blk * 4;
  // prologue: idx -> v prefetch (tile 0), u rows (tile 0), BN1 affine, stage B
  int m_cur = idx[(size_t)(tile * 8 + rn) * K_ + kk];
  uint4 PV[4];
  {
    const int n0 = tile * 8 + rn;
    const unsigned short* vp = v + (((size_t)(n0 >> 12) << 12) + m_cur) * O_ + ch;
#pragma unroll
    for (int jj = 0; jj < 4; ++jj) PV[jj] = *(const uint4*)(vp + jj * 8);
  }
  uint4 pu1;
  if (t < 128) {
    pu1 = *(const uint4*)(u + (size_t)tile * 1024 + t * 8);
    float s = 0.f, s2 = 0.f;
#pragma unroll
    for (int c = 0; c < 4; ++c) {           // 4 shadow copies
      s += stats1g[c * 256 + t];
      s2 += stats1g[c * 256 + 128 + t];
    }
    float mean = s * inv;
    float var = fmaf(-mean, mean, s2 * inv);
    float A = g1[t] * rsqrtf(var + EPS_);
    abl[t] = A;
    abl[O_ + t] = fmaf(-mean, A, b1[t]);
  }
  { // stage B: w2 (pre-converted bf16) row o, 32 cols, swizzled
    const int o = t >> 2, c0 = q * 32;
    const unsigned short* src = w2bf + o * 128 + c0;
#pragma unroll
    for (int jj = 0; jj < 4; ++jj) {
      uint4 val = *(const uint4*)(src + jj * 8);
      *(uint4*)(Bl + SWZ(o, o * 256 + (c0 + jj * 8) * 2)) = val;
    }
  }
  if (t < 128) *(uint4*)(ul + t * 8) = pu1;
  int m_next = idx[(size_t)((tile + 1) * 8 + rn) * K_ + kk];

  float sacc[4] = {0.f,0.f,0.f,0.f}, sacc2[4] = {0.f,0.f,0.f,0.f};
#pragma unroll
  for (int ti = 0; ti < 4; ++ti) {
    __syncthreads();   // staging (ul/Al writers) done; prev MFMA readers done
    { // stage A: a1[r][c] = relu((u+v)*A1 + B1) -> bf16, swizzled LDS
      const unsigned short* ulp = ul + rn * 128 + ch;   // wave-uniform row: broadcast
#pragma unroll
      for (int jj = 0; jj < 4; ++jj) {
        uint4 uu = *(const uint4*)(ulp + jj * 8);
        uint4 vv = PV[jj];
        const float* Ap = abl + ch + jj * 8;
        const float* Bp = abl + 128 + ch + jj * 8;
        float h0 = fmaxf(fmaf(bfl(uu.x) + bfl(vv.x), Ap[0], Bp[0]), 0.f);
        float h1 = fmaxf(fmaf(bfh(uu.x) + bfh(vv.x), Ap[1], Bp[1]), 0.f);
        float h2 = fmaxf(fmaf(bfl(uu.y) + bfl(vv.y), Ap[2], Bp[2]), 0.f);
        float h3 = fmaxf(fmaf(bfh(uu.y) + bfh(vv.y), Ap[3], Bp[3]), 0.f);
        float h4 = fmaxf(fmaf(bfl(uu.z) + bfl(vv.z), Ap[4], Bp[4]), 0.f);
        float h5 = fmaxf(fmaf(bfh(uu.z) + bfh(vv.z), Ap[5], Bp[5]), 0.f);
        float h6 = fmaxf(fmaf(bfl(uu.w) + bfl(vv.w), Ap[6], Bp[6]), 0.f);
        float h7 = fmaxf(fmaf(bfh(uu.w) + bfh(vv.w), Ap[7], Bp[7]), 0.f);
        *(uint4*)(Al + SWZ(r, r * 256 + (ch + jj * 8) * 2)) =
            make_uint4(pack2(h0,h1), pack2(h2,h3), pack2(h4,h5), pack2(h6,h7));
      }
    }
    __syncthreads();
    // prefetch next tile (loads in flight during MFMA + epilogue)
    if (ti < 3) {
      const int nn = (tile + 1) * 8 + rn;
      const unsigned short* vp = v + (((size_t)(nn >> 12) << 12) + m_next) * O_ + ch;
#pragma unroll
      for (int jj = 0; jj < 4; ++jj) PV[jj] = *(const uint4*)(vp + jj * 8);
      if (t < 128) pu1 = *(const uint4*)(u + (size_t)(tile + 1) * 1024 + t * 8);
    }
    if (ti < 2) m_next = idx[(size_t)((tile + 2) * 8 + rn) * K_ + kk];
    // MFMA: wave tile 32x64, 2x4 fragments x 4 k-steps
    f32x4 acc[2][4];
    f32x4 zero = {0.f, 0.f, 0.f, 0.f};
#pragma unroll
    for (int mi = 0; mi < 2; ++mi)
#pragma unroll
      for (int ni = 0; ni < 4; ++ni) acc[mi][ni] = zero;
#pragma unroll
    for (int ks = 0; ks < 4; ++ks) {
      const int cb = ks * 64 + kg * 16;
      s16x8 af[2], bf[4];
#pragma unroll
      for (int i = 0; i < 2; ++i) {
        const int ar = wm * 32 + i * 16 + r0;
        af[i] = *(const s16x8*)(Al + SWZ(ar, ar * 256 + cb));
      }
#pragma unroll
      for (int i = 0; i < 4; ++i) {
        const int br = wn * 64 + i * 16 + r0;
        bf[i] = *(const s16x8*)(Bl + SWZ(br, br * 256 + cb));
      }
#pragma unroll
      for (int mi = 0; mi < 2; ++mi)
#pragma unroll
        for (int ni = 0; ni < 4; ++ni)
          acc[mi][ni] = __builtin_amdgcn_mfma_f32_16x16x32_bf16(af[mi], bf[ni], acc[mi][ni], 0, 0, 0);
    }
    // write next tile's u rows (loads above have MFMA-time to land)
    if (ti < 3 && t < 128) *(uint4*)(ul + t * 8) = pu1;
    // epilogue: per-(n,o) max/min over the 16 k-rows + column sum/sumsq partials.
#pragma unroll
    for (int ni = 0; ni < 4; ++ni) {
      const int col = wn * 64 + ni * 16 + r0;
#pragma unroll
      for (int mi = 0; mi < 2; ++mi) {
        float a0 = acc[mi][ni][0], a1 = acc[mi][ni][1];
        float a2 = acc[mi][ni][2], a3 = acc[mi][ni][3];
        float mx = fmaxf(fmaxf(a0, a1), fmaxf(a2, a3));
        float mn = fminf(fminf(a0, a1), fminf(a2, a3));
        mx = fmaxf(mx, __shfl_xor(mx, 16));
        mx = fmaxf(mx, __shfl_xor(mx, 32));
        mn = fminf(mn, __shfl_xor(mn, 16));
        mn = fminf(mn, __shfl_xor(mn, 32));
        if (lane < 16)
          hmm[(size_t)(tile * 8 + wm * 2 + mi) * O_ + col] = pack2(mx, mn);
        sacc[ni] += (a0 + a1) + (a2 + a3);
        sacc2[ni] += fmaf(a0, a0, fmaf(a1, a1, fmaf(a2, a2, a3 * a3)));
      }
    }
    ++tile;
  }
  // column sums -> atomics (once per block)
#pragma unroll
  for (int ni = 0; ni < 4; ++ni) {
    float s = sacc[ni], s2 = sacc2[ni];
    s += __shfl_xor(s, 16);  s += __shfl_xor(s, 32);
    s2 += __shfl_xor(s2, 16); s2 += __shfl_xor(s2, 32);
    if (lane < 16) { cred[w][ni * 16 + r0][0] = s; cred[w][ni * 16 + r0][1] = s2; }
  }
  __syncthreads();
  if (t < 128) {
    const int o = t, wn0 = o >> 6, cl = o & 63;
    float s = 0.f, s2 = 0.f;
#pragma unroll
    for (int g = 0; g < 4; ++g) {
      s += cred[g * 2 + wn0][cl][0];
      s2 += cred[g * 2 + wn0][cl][1];
    }
    atomicAdd(&stats2g[o], s);
    atomicAdd(&stats2g[O_ + o], s2);
  }
}

// ---------------------------------------------------------------- finalize: BN2+ReLU+select
__global__ __launch_bounds__(256) void finalize_kernel(const uint32_t* __restrict__ hmm,
        const float* __restrict__ stats2g, const float* __restrict__ g2,
        const float* __restrict__ b2, float* __restrict__ out) {
  __shared__ float Af[128], Bf[128];
  const int t = threadIdx.x;
  if (t < 128) {
    const float inv = 1.0f / (float)ROWS_;
    float s = stats2g[t], s2 = stats2g[O_ + t];
    float mean = s * inv;
    float var = fmaf(-mean, mean, s2 * inv);
    float A = g2[t] * rsqrtf(var + EPS_);
    Af[t] = A;
    Bf[t] = fmaf(-mean, A, b2[t]);
  }
  __syncthreads();
#pragma unroll
  for (int rep = 0; rep < 2; ++rep) {
    const int f4 = blockIdx.x * 512 + rep * 256 + t;   // uint4 index, 524288 total
    uint4 p = ((const uint4*)hmm)[f4];
    const int c = (f4 & 31) * 4;
    float4 o4;
    { float A = Af[c+0], Bb = Bf[c+0]; float sel = (A >= 0.f) ? bfl(p.x) : bfh(p.x);
      o4.x = fmaxf(fmaf(A, sel, Bb), 0.f); }
    { float A = Af[c+1], Bb = Bf[c+1]; float sel = (A >= 0.f) ? bfl(p.y) : bfh(p.y);
      o4.y = fmaxf(fmaf(A, sel, Bb), 0.f); }
    { float A = Af[c+2], Bb = Bf[c+2]; float sel = (A >= 0.f) ? bfl(p.z) : bfh(p.z);
      o4.z = fmaxf(fmaf(A, sel, Bb), 0.f); }
    { float A = Af[c+3], Bb = Bf[c+3]; float sel = (A >= 0.f) ? bfl(p.w) : bfh(p.w);
      o4.w = fmaxf(fmaf(A, sel, Bb), 0.f); }
    ((float4*)out)[f4] = o4;
  }
}

extern "C" void kernel_launch(void* const* d_in, const int* in_sizes, int n_in,
                              void* d_out, int out_size, void* d_ws, size_t ws_size,
                              hipStream_t stream) {
  const float* feats = (const float*)d_in[0];
  const float* xyz   = (const float*)d_in[1];
  const float* w1    = (const float*)d_in[2];
  const float* g1    = (const float*)d_in[3];
  const float* b1    = (const float*)d_in[4];
  const float* w2    = (const float*)d_in[5];
  const float* g2    = (const float*)d_in[6];
  const float* b2    = (const float*)d_in[7];
  float* out = (float*)d_out;

  char* ws = (char*)d_ws;                                          // ~17 MB used
  int*            idx     = (int*)(ws + 0);                        // 1 MB
  unsigned short* u       = (unsigned short*)(ws + (1ull << 20));  // 4 MB bf16
  unsigned short* v       = (unsigned short*)(ws + (5ull << 20));  // 4 MB bf16
  uint32_t*       hmm     = (uint32_t*)(ws + (9ull << 20));        // 8 MB packed (mx|mn)
  float*          stats1g = (float*)(ws + (17ull << 20));          // 4 KB (4 copies)
  float*          stats2g = (float*)(ws + (17ull << 20) + 4096);   // 1 KB
  unsigned short* w2bf    = (unsigned short*)(ws + (17ull << 20) + 8192);  // 32 KB

  knn_kernel<<<256, 1024, 0, stream>>>(xyz, idx);
  uv_kernel<<<256, 256, 0, stream>>>(feats, w1, u, v, w2, w2bf, stats1g, stats2g);
  stats1_kernel<<<1024, 256, 0, stream>>>(u, v, idx, stats1g);
  gemm2_kernel<<<512, 512, 0, stream>>>(u, v, idx, stats1g, g1, b1, w2bf, stats2g, hmm);
  finalize_kernel<<<1024, 256, 0, stream>>>(hmm, stats2g, g2, b2, out);
}